// Round 5
// baseline (278.590 us; speedup 1.0000x reference)
//
#include <hip/hip_runtime.h>
#include <hip/hip_bf16.h>

typedef unsigned short u16;

#define D_KEY   128
#define BANK_N  9720
#define BANK_P  9728   /* 76*128 */
#define N_TOK   1620
#define N_PAD   1664   /* 13*128 */
#define OBJ_N   3
#define M_ROWS  1539   /* 3*512 + 3 mask rows */
#define M_PAD   1664
#define LDCOL   1664
#define TOTV    14929920u  /* 3*512*9720 floats in values */
#define TOTM    29160u     /* 3*9720 floats in masks */
#define QK_SCALE 0.08838834764831845f

typedef __bf16 bf16x8 __attribute__((ext_vector_type(8)));
typedef float  f32x4  __attribute__((ext_vector_type(4)));
typedef unsigned int u32x4 __attribute__((ext_vector_type(4)));

__device__ __forceinline__ float bf2f(u16 u) {
  union { unsigned int i; float f; } v; v.i = ((unsigned int)u) << 16; return v.f;
}
__device__ __forceinline__ u16 f2bf(float f) {
  unsigned int x = __float_as_uint(f);
  unsigned int r = x + 0x7fffu + ((x >> 16) & 1u);  // RNE
  return (u16)(r >> 16);
}

__device__ __forceinline__ void load_lds16(const void* g, void* l) {
  __builtin_amdgcn_global_load_lds(
      (const __attribute__((address_space(1))) void*)g,
      (__attribute__((address_space(3))) void*)l, 16, 0, 0);
}

// ---------------- prep kernels ----------------
__global__ void cast_qT(const float* __restrict__ q, u16* __restrict__ qT,
                        float* __restrict__ lsum) {
  int idx = blockIdx.x * 256 + threadIdx.x;          // N_PAD*128
  if (idx < N_PAD) lsum[idx] = 0.f;                  // zero row-sum accumulator
  if (idx >= N_PAD * D_KEY) return;
  int n = idx >> 7, d = idx & 127;
  float v = (n < N_TOK) ? q[d * N_TOK + n] * QK_SCALE : 0.f;
  qT[idx] = f2bf(v);
}

// LDS-tiled transpose: keys[d][bank] (fp32) -> kT[bank][d] (bf16)
__global__ void transpose_keys(const float* __restrict__ keys, u16* __restrict__ kT) {
  __shared__ float t[64][65];
  const int bk = blockIdx.x * 64;
  const int bd = blockIdx.y * 64;
  const int tx = threadIdx.x & 63;
  const int ty = threadIdx.x >> 6;
#pragma unroll
  for (int i = 0; i < 64; i += 4) {
    int d = bd + ty + i;
    int k = bk + tx;
    t[ty + i][tx] = (k < BANK_N) ? keys[(size_t)d * BANK_N + k] : 0.f;
  }
  __syncthreads();
#pragma unroll
  for (int i = 0; i < 64; i += 4) {
    int r = ty + i;
    kT[(size_t)(bk + r) * D_KEY + bd + tx] = f2bf(t[tx][r]);
  }
}

// ---------------- QK GEMM: E[n][k] = exp(qT[n][:].kT[k][:]), pad cols -> 0 ----------------
__global__ void gemm_qk(const u16* __restrict__ A, const u16* __restrict__ B,
                        u16* __restrict__ E, float* __restrict__ lsum)
{
  __shared__ __align__(16) u16 sbuf[16384];   // As(8K u16) + Bs(8K u16); C-stage aliases all
  u16* As = sbuf;
  u16* Bs = sbuf + 4096;

  const int tid  = threadIdx.x;
  const int wave = tid >> 6;
  const int lane = tid & 63;
  const int bn = blockIdx.x, bm = blockIdx.y;

  const u16* Abase = A + (size_t)bm * 128 * D_KEY;
  const u16* Bbase = B + (size_t)bn * 128 * D_KEY;

  const int r  = lane >> 2;
  const int c8 = (lane & 3) << 3;
  const int s0 = wave, s1 = wave + 4;

  f32x4 acc[4][4];
#pragma unroll
  for (int i = 0; i < 4; i++)
#pragma unroll
    for (int j = 0; j < 4; j++) acc[i][j] = (f32x4){0.f, 0.f, 0.f, 0.f};

  const int m_in = lane & 15;
  const int quad = lane >> 4;
  const int wm = (wave >> 1) * 64;
  const int wn = (wave & 1) * 64;

  for (int kt = 0; kt < D_KEY; kt += 32) {
    load_lds16(Abase + (size_t)(s0 * 16 + r) * D_KEY + kt + c8, &As[s0 * 512]);
    load_lds16(Abase + (size_t)(s1 * 16 + r) * D_KEY + kt + c8, &As[s1 * 512]);
    load_lds16(Bbase + (size_t)(s0 * 16 + r) * D_KEY + kt + c8, &Bs[s0 * 512]);
    load_lds16(Bbase + (size_t)(s1 * 16 + r) * D_KEY + kt + c8, &Bs[s1 * 512]);
    __syncthreads();

    bf16x8 af[4], bfr[4];
#pragma unroll
    for (int i = 0; i < 4; i++)
      af[i] = *(const bf16x8*)&As[(wm + i * 16 + m_in) * 32 + quad * 8];
#pragma unroll
    for (int j = 0; j < 4; j++)
      bfr[j] = *(const bf16x8*)&Bs[(wn + j * 16 + m_in) * 32 + quad * 8];
#pragma unroll
    for (int i = 0; i < 4; i++)
#pragma unroll
      for (int j = 0; j < 4; j++)
        acc[i][j] = __builtin_amdgcn_mfma_f32_16x16x32_bf16(af[i], bfr[j], acc[i][j], 0, 0, 0);
    __syncthreads();
  }

  // exp + row-sum + zero pad cols; stage in LDS; coalesced store
  float rs[4][4];
#pragma unroll
  for (int i = 0; i < 4; i++)
#pragma unroll
    for (int t = 0; t < 4; t++) rs[i][t] = 0.f;

#pragma unroll
  for (int i = 0; i < 4; i++)
#pragma unroll
    for (int j = 0; j < 4; j++)
#pragma unroll
      for (int t = 0; t < 4; t++) {
        int row_l = wm + i * 16 + quad * 4 + t;   // D layout: col=lane&15, row=quad*4+t [m89]
        int col_l = wn + j * 16 + m_in;
        float e = __expf(acc[i][j][t]);
        bool valid = (bn * 128 + col_l) < BANK_N;
        if (valid) rs[i][t] += e;
        sbuf[(row_l << 7) + col_l] = valid ? f2bf(e) : (u16)0;  // E=0 in pad cols (critical!)
      }

#pragma unroll
  for (int i = 0; i < 4; i++)
#pragma unroll
    for (int t = 0; t < 4; t++) {
      float rv = rs[i][t];
      rv += __shfl_xor(rv, 1);
      rv += __shfl_xor(rv, 2);
      rv += __shfl_xor(rv, 4);
      rv += __shfl_xor(rv, 8);
      if ((lane & 15) == 0)
        atomicAdd(&lsum[bm * 128 + wm + i * 16 + quad * 4 + t], rv);
    }
  __syncthreads();

  for (int chunk = tid; chunk < 2048; chunk += 256) {
    int row = chunk >> 4;
    int cu  = (chunk & 15) << 3;
    u32x4 v = *(const u32x4*)&sbuf[(row << 7) + cu];
    *(u32x4*)&E[(size_t)(bm * 128 + row) * BANK_P + bn * 128 + cu] = v;
  }
}

// ---------------- PV GEMM: memC[bz][m][n] = sum_k vm[m][k]*E[n][k] ----------------
// A = values/masks fp32 read DIRECTLY (no cast kernel); XOR-swizzled fp32 LDS tile,
// cvt->bf16 at fragment build. B = E bf16. Split-K with bz = blockIdx % nParts (XCD-aligned).
__global__ void gemm_pv(const float* __restrict__ values, const float* __restrict__ masks,
                        const u16* __restrict__ E, u16* __restrict__ memC,
                        int nParts, int kChunk, size_t cPartStride)
{
  __shared__ __align__(16) u16 sbuf[16384];   // As_f 16K + Bs 8K; C-stage aliases 32K
  float* As_f = (float*)sbuf;                 // 128 x 32 fp32, col-group XOR row&7 swizzle
  u16*   Bs   = sbuf + 8192;                  // 128 x 32 bf16

  const int tid  = threadIdx.x;
  const int wave = tid >> 6;
  const int lane = tid & 63;

  int b = blockIdx.x;
  int bz = b % nParts;                        // consecutive blocks -> XCD round-robin
  int rr = b / nParts;
  int gid = rr / 52;
  int rem = rr - gid * 52;
  int width = (gid < 3) ? 4 : 1;
  int bm = rem / width;
  int bn = gid * 4 + (rem - bm * width);

  const int kbeg = bz * kChunk;

  // A staging: 4 wave-instrs, 8 rows x 32 fp32 each; lane covers (row=l>>3, colgrp=(l&7)^row)
  const int arow_l = lane >> 3;
  const unsigned acol = (unsigned)(((lane & 7) ^ arow_l) << 2);
  const float* asrc[4];
  unsigned aoff[4], alim[4];
  float* albase[4];
#pragma unroll
  for (int t = 0; t < 4; t++) {
    int row_l = wave * 32 + t * 8 + arow_l;
    int r_g = bm * 128 + row_l;
    if (r_g < 1536) { asrc[t] = values; aoff[t] = (unsigned)r_g * 9720u; alim[t] = TOTV - 4u; }
    else {
      int mi = r_g - 1536; if (mi > 2) mi = 2;     // clamp pad rows to masks row 2 (C rows unread)
      asrc[t] = masks; aoff[t] = (unsigned)mi * 9720u; alim[t] = TOTM - 4u;
    }
    aoff[t] += (unsigned)kbeg + acol;
    albase[t] = As_f + (wave * 32 + t * 8) * 32;
  }
  // B staging: 2 wave-instrs, 16 rows x 32 bf16 each
  const u16* bsrc[2];
  u16* blbase[2];
#pragma unroll
  for (int s = 0; s < 2; s++) {
    int seg = wave + s * 4;
    int row = bn * 128 + seg * 16 + (lane >> 2);
    bsrc[s] = E + (size_t)row * BANK_P + kbeg + ((lane & 3) << 3);
    blbase[s] = Bs + seg * 16 * 32;
  }

  f32x4 acc[4][4];
#pragma unroll
  for (int i = 0; i < 4; i++)
#pragma unroll
    for (int j = 0; j < 4; j++) acc[i][j] = (f32x4){0.f, 0.f, 0.f, 0.f};

  const int m_in = lane & 15;
  const int quad = lane >> 4;
  const int wm = (wave >> 1) * 64;
  const int wn = (wave & 1) * 64;
  const int slot0 = (2 * quad) ^ (m_in & 7);   // un-swizzle for frag read
  const int slot1 = slot0 ^ 1;

  for (int kt = 0; kt < kChunk; kt += 32) {
#pragma unroll
    for (int t = 0; t < 4; t++) {
      unsigned off = aoff[t] + (unsigned)kt;
      off = off > alim[t] ? alim[t] : off;    // tail clamp (E=0 there, product=0)
      load_lds16(asrc[t] + off, albase[t]);
    }
#pragma unroll
    for (int s = 0; s < 2; s++)
      load_lds16(bsrc[s] + kt, blbase[s]);
    __syncthreads();

    bf16x8 af[4], bfr[4];
#pragma unroll
    for (int i = 0; i < 4; i++) {
      const float* rowp = As_f + (wm + i * 16 + m_in) * 32;
      f32x4 a0 = *(const f32x4*)(rowp + slot0 * 4);
      f32x4 a1 = *(const f32x4*)(rowp + slot1 * 4);
      bf16x8 v;
      v[0] = (__bf16)a0[0]; v[1] = (__bf16)a0[1]; v[2] = (__bf16)a0[2]; v[3] = (__bf16)a0[3];
      v[4] = (__bf16)a1[0]; v[5] = (__bf16)a1[1]; v[6] = (__bf16)a1[2]; v[7] = (__bf16)a1[3];
      af[i] = v;
    }
#pragma unroll
    for (int j = 0; j < 4; j++)
      bfr[j] = *(const bf16x8*)&Bs[(wn + j * 16 + m_in) * 32 + quad * 8];
#pragma unroll
    for (int i = 0; i < 4; i++)
#pragma unroll
      for (int j = 0; j < 4; j++)
        acc[i][j] = __builtin_amdgcn_mfma_f32_16x16x32_bf16(af[i], bfr[j], acc[i][j], 0, 0, 0);
    __syncthreads();
  }

  // C-stage in LDS (bf16), coalesced NT store
#pragma unroll
  for (int i = 0; i < 4; i++)
#pragma unroll
    for (int j = 0; j < 4; j++)
#pragma unroll
      for (int t = 0; t < 4; t++) {
        int row_l = wm + i * 16 + quad * 4 + t;
        int col_l = wn + j * 16 + m_in;
        sbuf[(row_l << 7) + col_l] = f2bf(acc[i][j][t]);
      }
  __syncthreads();

  u16* Cg = memC + (size_t)bz * cPartStride;
  for (int chunk = tid; chunk < 2048; chunk += 256) {
    int row = chunk >> 4;
    int cu  = (chunk & 15) << 3;
    u32x4 v = *(const u32x4*)&sbuf[(row << 7) + cu];
    __builtin_nontemporal_store(v, (u32x4*)&Cg[(size_t)(bm * 128 + row) * LDCOL + bn * 128 + cu]);
  }
}

// ---------------- epilogue: vec4 over n; sum partials, /lsum, q_out product ----------------
__global__ void epilogue(const u16* __restrict__ memC, const float* __restrict__ q_out,
                         const float* __restrict__ lsum, float* __restrict__ out, int nParts) {
  const int NV = N_TOK / 4;                     // 405
  int idx = blockIdx.x * 256 + threadIdx.x;
  if (idx >= OBJ_N * 1024 * NV) return;
  int n4 = (idx % NV) * 4;
  int t = idx / NV;
  int c = t & 1023;
  int o = t >> 10;
  const size_t ps = (size_t)M_PAD * LDCOL;

  size_t rowoff = (c < 512) ? (size_t)(o * 512 + c) * LDCOL
                            : (size_t)(1536 + o) * LDCOL;
  const u16* base = memC + rowoff + n4;
  float4 s = make_float4(0.f, 0.f, 0.f, 0.f);
  for (int z = 0; z < nParts; z++) {
    ushort4 v = *(const ushort4*)(base + z * ps);
    s.x += bf2f(v.x); s.y += bf2f(v.y); s.z += bf2f(v.z); s.w += bf2f(v.w);
  }
  float4 r;
  float ix = 1.f / lsum[n4], iy = 1.f / lsum[n4 + 1],
        iz = 1.f / lsum[n4 + 2], iw = 1.f / lsum[n4 + 3];
  if (c < 512) {
    r.x = s.x * ix; r.y = s.y * iy; r.z = s.z * iz; r.w = s.w * iw;
  } else {
    float4 q = *(const float4*)(q_out + (size_t)(o * 512 + (c - 512)) * N_TOK + n4);
    r.x = q.x * s.x * ix; r.y = q.y * s.y * iy;
    r.z = q.z * s.z * iz; r.w = q.w * s.w * iw;
  }
  *(float4*)(out + (size_t)(o * 1024 + c) * N_TOK + n4) = r;
}

extern "C" void kernel_launch(void* const* d_in, const int* in_sizes, int n_in,
                              void* d_out, int out_size, void* d_ws, size_t ws_size,
                              hipStream_t stream) {
  const float* keys   = (const float*)d_in[0];
  const float* q_in   = (const float*)d_in[1];
  const float* q_out  = (const float*)d_in[2];
  const float* values = (const float*)d_in[3];
  const float* masks  = (const float*)d_in[4];
  float* out = (float*)d_out;

  char* ws = (char*)d_ws;
  size_t off = 0;
  auto alloc = [&](size_t bytes) -> void* {
    void* p = ws + off; off += (bytes + 255) & ~(size_t)255; return p;
  };
  u16*   qT   = (u16*)alloc((size_t)N_PAD * D_KEY * 2);
  u16*   kT   = (u16*)alloc((size_t)BANK_P * D_KEY * 2);
  u16*   E    = (u16*)alloc((size_t)N_PAD * BANK_P * 2);
  float* lsum = (float*)alloc((size_t)N_PAD * 4);

  int nParts = 8;
  while (nParts > 1 && off + (size_t)nParts * M_PAD * LDCOL * 2 > ws_size) nParts >>= 1;
  u16* memC = (u16*)alloc((size_t)nParts * M_PAD * LDCOL * 2);

  cast_qT<<<(N_PAD * D_KEY + 255) / 256, 256, 0, stream>>>(q_in, qT, lsum);
  transpose_keys<<<dim3(BANK_P / 64, D_KEY / 64), 256, 0, stream>>>(keys, kT);

  gemm_qk<<<dim3(BANK_P / 128, N_PAD / 128), 256, 0, stream>>>(qT, kT, E, lsum);

  int kChunk = BANK_P / nParts;
  gemm_pv<<<dim3(169 * nParts), 256, 0, stream>>>(
      values, masks, E, memC, nParts, kChunk, (size_t)M_PAD * LDCOL);

  epilogue<<<(OBJ_N * 1024 * (N_TOK / 4) + 255) / 256, 256, 0, stream>>>(
      memC, q_out, lsum, out, nParts);
}

// Round 6
// 241.619 us; speedup vs baseline: 1.1530x; 1.1530x over previous
//
#include <hip/hip_runtime.h>
#include <hip/hip_bf16.h>

typedef unsigned short u16;

#define D_KEY   128
#define BANK_N  9720
#define BANK_P  9728   /* 76*128 */
#define N_TOK   1620
#define N_PAD   1664   /* 13*128 */
#define OBJ_N   3
#define M_PAD   1664
#define LDCOL   1664
#define ONES_ROW 1539  /* vm row of 1.0 -> PV computes lsum as C row 1539 */
#define QK_SCALE 0.08838834764831845f

typedef __bf16 bf16x8 __attribute__((ext_vector_type(8)));
typedef float  f32x4  __attribute__((ext_vector_type(4)));
typedef unsigned int u32x4 __attribute__((ext_vector_type(4)));

__device__ __forceinline__ float bf2f(u16 u) {
  union { unsigned int i; float f; } v; v.i = ((unsigned int)u) << 16; return v.f;
}
__device__ __forceinline__ u16 f2bf(float f) {
  unsigned int x = __float_as_uint(f);
  unsigned int r = x + 0x7fffu + ((x >> 16) & 1u);  // RNE
  return (u16)(r >> 16);
}

__device__ __forceinline__ void load_lds16(const void* g, void* l) {
  __builtin_amdgcn_global_load_lds(
      (const __attribute__((address_space(1))) void*)g,
      (__attribute__((address_space(3))) void*)l, 16, 0, 0);
}

// ---------------- prep: qT cast (blocks 0..831) + keys transpose (blocks 832..1135) ----------------
__global__ void prep(const float* __restrict__ q, const float* __restrict__ keys,
                     u16* __restrict__ qT, u16* __restrict__ kT) {
  __shared__ float t[64][65];
  int b = blockIdx.x;
  if (b < 832) {                                   // qT: N_PAD*128 elems
    int idx = b * 256 + threadIdx.x;
    int n = idx >> 7, d = idx & 127;
    float v = (n < N_TOK) ? q[d * N_TOK + n] * QK_SCALE : 0.f;
    qT[idx] = f2bf(v);
    return;
  }
  b -= 832;                                        // transpose: 152 x 2 tiles
  const int bk = (b % 152) * 64;
  const int bd = (b / 152) * 64;
  const int tx = threadIdx.x & 63;
  const int ty = threadIdx.x >> 6;
#pragma unroll
  for (int i = 0; i < 64; i += 4) {
    int d = bd + ty + i;
    int k = bk + tx;
    t[ty + i][tx] = (k < BANK_N) ? keys[(size_t)d * BANK_N + k] : 0.f;
  }
  __syncthreads();
#pragma unroll
  for (int i = 0; i < 64; i += 4) {
    int r = ty + i;
    kT[(size_t)(bk + r) * D_KEY + bd + tx] = f2bf(t[tx][r]);
  }
}

// ---------------- cast_vm: values/masks fp32 -> vm bf16; row 1539 = ones ----------------
__global__ void cast_vm(const float* __restrict__ values, const float* __restrict__ masks,
                        u16* __restrict__ vm) {
  const int NV = BANK_P / 4;
  int idx = blockIdx.x * 256 + threadIdx.x;
  if (idx >= M_PAD * NV) return;
  int m = idx / NV;
  int k4 = (idx - m * NV) * 4;
  float4 v = make_float4(0.f, 0.f, 0.f, 0.f);
  if (m == ONES_ROW) {
    v.x = (k4     < BANK_N) ? 1.f : 0.f;
    v.y = (k4 + 1 < BANK_N) ? 1.f : 0.f;
    v.z = (k4 + 2 < BANK_N) ? 1.f : 0.f;
    v.w = (k4 + 3 < BANK_N) ? 1.f : 0.f;
  } else {
    const float* src = nullptr;
    if (m < 1536)          src = values + (size_t)m * BANK_N;
    else if (m < ONES_ROW) src = masks + (size_t)(m - 1536) * BANK_N;
    if (src) {
      if (k4 + 3 < BANK_N) v = *(const float4*)(src + k4);
      else {
        if (k4     < BANK_N) v.x = src[k4];
        if (k4 + 1 < BANK_N) v.y = src[k4 + 1];
        if (k4 + 2 < BANK_N) v.z = src[k4 + 2];
        if (k4 + 3 < BANK_N) v.w = src[k4 + 3];
      }
    }
  }
  ushort4 o;
  o.x = f2bf(v.x); o.y = f2bf(v.y); o.z = f2bf(v.z); o.w = f2bf(v.w);
  *(ushort4*)(vm + (size_t)m * BANK_P + k4) = o;
}

// ---------------- QK GEMM: E[n][k] = exp(qT[n][:].kT[k][:]); pad cols -> 0; no atomics ----------------
__global__ void gemm_qk(const u16* __restrict__ A, const u16* __restrict__ B,
                        u16* __restrict__ E)
{
  __shared__ __align__(16) u16 sbuf[16384];
  u16* As = sbuf;
  u16* Bs = sbuf + 4096;

  const int tid  = threadIdx.x;
  const int wave = tid >> 6;
  const int lane = tid & 63;
  const int bn = blockIdx.x, bm = blockIdx.y;

  const u16* Abase = A + (size_t)bm * 128 * D_KEY;
  const u16* Bbase = B + (size_t)bn * 128 * D_KEY;

  const int r  = lane >> 2;
  const int c8 = (lane & 3) << 3;
  const int s0 = wave, s1 = wave + 4;

  f32x4 acc[4][4];
#pragma unroll
  for (int i = 0; i < 4; i++)
#pragma unroll
    for (int j = 0; j < 4; j++) acc[i][j] = (f32x4){0.f, 0.f, 0.f, 0.f};

  const int m_in = lane & 15;
  const int quad = lane >> 4;
  const int wm = (wave >> 1) * 64;
  const int wn = (wave & 1) * 64;

  for (int kt = 0; kt < D_KEY; kt += 32) {
    load_lds16(Abase + (size_t)(s0 * 16 + r) * D_KEY + kt + c8, &As[s0 * 512]);
    load_lds16(Abase + (size_t)(s1 * 16 + r) * D_KEY + kt + c8, &As[s1 * 512]);
    load_lds16(Bbase + (size_t)(s0 * 16 + r) * D_KEY + kt + c8, &Bs[s0 * 512]);
    load_lds16(Bbase + (size_t)(s1 * 16 + r) * D_KEY + kt + c8, &Bs[s1 * 512]);
    __syncthreads();

    bf16x8 af[4], bfr[4];
#pragma unroll
    for (int i = 0; i < 4; i++)
      af[i] = *(const bf16x8*)&As[(wm + i * 16 + m_in) * 32 + quad * 8];
#pragma unroll
    for (int j = 0; j < 4; j++)
      bfr[j] = *(const bf16x8*)&Bs[(wn + j * 16 + m_in) * 32 + quad * 8];
#pragma unroll
    for (int i = 0; i < 4; i++)
#pragma unroll
      for (int j = 0; j < 4; j++)
        acc[i][j] = __builtin_amdgcn_mfma_f32_16x16x32_bf16(af[i], bfr[j], acc[i][j], 0, 0, 0);
    __syncthreads();
  }

  // exp, zero pad cols; stage in LDS; coalesced store
#pragma unroll
  for (int i = 0; i < 4; i++)
#pragma unroll
    for (int j = 0; j < 4; j++)
#pragma unroll
      for (int t = 0; t < 4; t++) {
        int row_l = wm + i * 16 + quad * 4 + t;   // D layout: col=lane&15, row=quad*4+t [m89]
        int col_l = wn + j * 16 + m_in;
        bool valid = (bn * 128 + col_l) < BANK_N;
        sbuf[(row_l << 7) + col_l] = valid ? f2bf(__expf(acc[i][j][t])) : (u16)0;
      }
  __syncthreads();

  for (int chunk = tid; chunk < 2048; chunk += 256) {
    int row = chunk >> 4;
    int cu  = (chunk & 15) << 3;
    u32x4 v = *(const u32x4*)&sbuf[(row << 7) + cu];
    *(u32x4*)&E[(size_t)(bm * 128 + row) * BANK_P + bn * 128 + cu] = v;
  }
}

// ---------------- PV GEMM (R4-fast inner loop): memC[bz][m][n] = sum_k vm[m][k]*E[n][k] ----------------
__global__ void gemm_pv(const u16* __restrict__ A, const u16* __restrict__ B,
                        u16* __restrict__ memC, int kChunk, size_t cPartStride)
{
  __shared__ __align__(16) u16 sbuf[16384];   // As 8K + Bs 8K; C-stage aliases 32K
  u16* As = sbuf;
  u16* Bs = sbuf + 4096;

  const int tid  = threadIdx.x;
  const int wave = tid >> 6;
  const int lane = tid & 63;

  int b = blockIdx.x;
  int bz = b / 169;                           // R4 decode (measured-fast)
  int rr = b - bz * 169;
  int gid = rr / 52;
  int rem = rr - gid * 52;
  int width = (gid < 3) ? 4 : 1;
  int bm = rem / width;
  int bn = gid * 4 + (rem - bm * width);

  const int kbeg = bz * kChunk;
  const int kend = kbeg + kChunk;

  const u16* Abase = A + (size_t)bm * 128 * BANK_P;
  const u16* Bbase = B + (size_t)bn * 128 * BANK_P;

  const int r  = lane >> 2;
  const int c8 = (lane & 3) << 3;
  const int s0 = wave, s1 = wave + 4;

  f32x4 acc[4][4];
#pragma unroll
  for (int i = 0; i < 4; i++)
#pragma unroll
    for (int j = 0; j < 4; j++) acc[i][j] = (f32x4){0.f, 0.f, 0.f, 0.f};

  const int m_in = lane & 15;
  const int quad = lane >> 4;
  const int wm = (wave >> 1) * 64;
  const int wn = (wave & 1) * 64;

  for (int kt = kbeg; kt < kend; kt += 32) {
    load_lds16(Abase + (size_t)(s0 * 16 + r) * BANK_P + kt + c8, &As[s0 * 512]);
    load_lds16(Abase + (size_t)(s1 * 16 + r) * BANK_P + kt + c8, &As[s1 * 512]);
    load_lds16(Bbase + (size_t)(s0 * 16 + r) * BANK_P + kt + c8, &Bs[s0 * 512]);
    load_lds16(Bbase + (size_t)(s1 * 16 + r) * BANK_P + kt + c8, &Bs[s1 * 512]);
    __syncthreads();

    bf16x8 af[4], bfr[4];
#pragma unroll
    for (int i = 0; i < 4; i++)
      af[i] = *(const bf16x8*)&As[(wm + i * 16 + m_in) * 32 + quad * 8];
#pragma unroll
    for (int j = 0; j < 4; j++)
      bfr[j] = *(const bf16x8*)&Bs[(wn + j * 16 + m_in) * 32 + quad * 8];
#pragma unroll
    for (int i = 0; i < 4; i++)
#pragma unroll
      for (int j = 0; j < 4; j++)
        acc[i][j] = __builtin_amdgcn_mfma_f32_16x16x32_bf16(af[i], bfr[j], acc[i][j], 0, 0, 0);
    __syncthreads();
  }

  // C-stage in LDS (bf16), coalesced NT store
#pragma unroll
  for (int i = 0; i < 4; i++)
#pragma unroll
    for (int j = 0; j < 4; j++)
#pragma unroll
      for (int t = 0; t < 4; t++) {
        int row_l = wm + i * 16 + quad * 4 + t;
        int col_l = wn + j * 16 + m_in;
        sbuf[(row_l << 7) + col_l] = f2bf(acc[i][j][t]);
      }
  __syncthreads();

  u16* Cg = memC + (size_t)bz * cPartStride;
  for (int chunk = tid; chunk < 2048; chunk += 256) {
    int row = chunk >> 4;
    int cu  = (chunk & 15) << 3;
    u32x4 v = *(const u32x4*)&sbuf[(row << 7) + cu];
    __builtin_nontemporal_store(v, (u32x4*)&Cg[(size_t)(bm * 128 + row) * LDCOL + bn * 128 + cu]);
  }
}

// ---------------- epilogue: vec4 over n; lsum from memC row ONES_ROW ----------------
__global__ void epilogue(const u16* __restrict__ memC, const float* __restrict__ q_out,
                         float* __restrict__ out, int nParts) {
  const int NV = N_TOK / 4;                     // 405
  int idx = blockIdx.x * 256 + threadIdx.x;
  if (idx >= OBJ_N * 1024 * NV) return;
  int n4 = (idx % NV) * 4;
  int t = idx / NV;
  int c = t & 1023;
  int o = t >> 10;
  const size_t ps = (size_t)M_PAD * LDCOL;

  // lsum from the ones-row (L2-hot: 26 KB unique)
  const u16* lbase = memC + (size_t)ONES_ROW * LDCOL + n4;
  float4 l = make_float4(0.f, 0.f, 0.f, 0.f);
  for (int z = 0; z < nParts; z++) {
    ushort4 v = *(const ushort4*)(lbase + z * ps);
    l.x += bf2f(v.x); l.y += bf2f(v.y); l.z += bf2f(v.z); l.w += bf2f(v.w);
  }

  size_t rowoff = (c < 512) ? (size_t)(o * 512 + c) * LDCOL
                            : (size_t)(1536 + o) * LDCOL;
  const u16* base = memC + rowoff + n4;
  float4 s = make_float4(0.f, 0.f, 0.f, 0.f);
  for (int z = 0; z < nParts; z++) {
    ushort4 v = *(const ushort4*)(base + z * ps);
    s.x += bf2f(v.x); s.y += bf2f(v.y); s.z += bf2f(v.z); s.w += bf2f(v.w);
  }
  float4 rv;
  float ix = 1.f / l.x, iy = 1.f / l.y, iz = 1.f / l.z, iw = 1.f / l.w;
  if (c < 512) {
    rv.x = s.x * ix; rv.y = s.y * iy; rv.z = s.z * iz; rv.w = s.w * iw;
  } else {
    float4 q = *(const float4*)(q_out + (size_t)(o * 512 + (c - 512)) * N_TOK + n4);
    rv.x = q.x * s.x * ix; rv.y = q.y * s.y * iy;
    rv.z = q.z * s.z * iz; rv.w = q.w * s.w * iw;
  }
  *(float4*)(out + (size_t)(o * 1024 + c) * N_TOK + n4) = rv;
}

extern "C" void kernel_launch(void* const* d_in, const int* in_sizes, int n_in,
                              void* d_out, int out_size, void* d_ws, size_t ws_size,
                              hipStream_t stream) {
  const float* keys   = (const float*)d_in[0];
  const float* q_in   = (const float*)d_in[1];
  const float* q_out  = (const float*)d_in[2];
  const float* values = (const float*)d_in[3];
  const float* masks  = (const float*)d_in[4];
  float* out = (float*)d_out;

  char* ws = (char*)d_ws;
  size_t off = 0;
  auto alloc = [&](size_t bytes) -> void* {
    void* p = ws + off; off += (bytes + 255) & ~(size_t)255; return p;
  };
  u16* qT = (u16*)alloc((size_t)N_PAD * D_KEY * 2);
  u16* kT = (u16*)alloc((size_t)BANK_P * D_KEY * 2);
  u16* vm = (u16*)alloc((size_t)M_PAD * BANK_P * 2);
  u16* E  = (u16*)alloc((size_t)N_PAD * BANK_P * 2);

  int nParts = 8;
  while (nParts > 1 && off + (size_t)nParts * M_PAD * LDCOL * 2 > ws_size) nParts >>= 1;
  u16* memC = (u16*)alloc((size_t)nParts * M_PAD * LDCOL * 2);

  prep<<<832 + 304, 256, 0, stream>>>(q_in, keys, qT, kT);
  cast_vm<<<(M_PAD * (BANK_P / 4) + 255) / 256, 256, 0, stream>>>(values, masks, vm);

  gemm_qk<<<dim3(BANK_P / 128, N_PAD / 128), 256, 0, stream>>>(qT, kT, E);

  int kChunk = BANK_P / nParts;
  gemm_pv<<<dim3(169 * nParts), 256, 0, stream>>>(vm, E, memC, kChunk, (size_t)M_PAD * LDCOL);

  epilogue<<<(OBJ_N * 1024 * (N_TOK / 4) + 255) / 256, 256, 0, stream>>>(
      memC, q_out, out, nParts);
}

// Round 7
// 229.360 us; speedup vs baseline: 1.2146x; 1.0534x over previous
//
#include <hip/hip_runtime.h>
#include <hip/hip_bf16.h>

typedef unsigned short u16;
typedef unsigned char  u8;

#define D_KEY   128
#define BANK_N  9720
#define BANK_P  9728   /* 76*128 */
#define N_TOK   1620
#define N_PAD   1664   /* 13*128 */
#define OBJ_N   3
#define M_PAD   1664
#define LDCOL   1664
#define ONES_ROW 1539  /* vm row of 1.0 -> PV computes lsum as C row 1539 */
#define QK_SCALE 0.08838834764831845f

typedef __bf16 bf16x8 __attribute__((ext_vector_type(8)));
typedef float  f32x4  __attribute__((ext_vector_type(4)));
typedef unsigned int u32x4 __attribute__((ext_vector_type(4)));

__device__ __forceinline__ float bf2f(u16 u) {
  union { unsigned int i; float f; } v; v.i = ((unsigned int)u) << 16; return v.f;
}
__device__ __forceinline__ u16 f2bf(float f) {
  unsigned int x = __float_as_uint(f);
  unsigned int r = x + 0x7fffu + ((x >> 16) & 1u);  // RNE
  return (u16)(r >> 16);
}
__device__ __forceinline__ unsigned pack_fp8x4(float a, float b, float c, float d) {
  unsigned v = __builtin_amdgcn_cvt_pk_fp8_f32(a, b, 0, false);
  v = __builtin_amdgcn_cvt_pk_fp8_f32(c, d, v, true);
  return v;
}
__device__ __forceinline__ u8 f2fp8(float a) {
  return (u8)(__builtin_amdgcn_cvt_pk_fp8_f32(a, 0.f, 0, false) & 0xff);
}

__device__ __forceinline__ void load_lds16(const void* g, void* l) {
  __builtin_amdgcn_global_load_lds(
      (const __attribute__((address_space(1))) void*)g,
      (__attribute__((address_space(3))) void*)l, 16, 0, 0);
}

// ---- prep: qT cast (0..831) + keys transpose (832..1135) + vm8 fp8 cast (1136..) ----
__global__ void prep(const float* __restrict__ q, const float* __restrict__ keys,
                     const float* __restrict__ values, const float* __restrict__ masks,
                     u16* __restrict__ qT, u16* __restrict__ kT, u8* __restrict__ vm8) {
  __shared__ float t[64][65];
  int b = blockIdx.x;
  if (b < 832) {                                   // qT: N_PAD*128 elems
    int idx = b * 256 + threadIdx.x;
    int n = idx >> 7, d = idx & 127;
    float v = (n < N_TOK) ? q[d * N_TOK + n] * QK_SCALE : 0.f;
    qT[idx] = f2bf(v);
    return;
  }
  if (b < 1136) {                                  // keys transpose: 152 x 2 tiles
    b -= 832;
    const int bk = (b % 152) * 64;
    const int bd = (b / 152) * 64;
    const int tx = threadIdx.x & 63;
    const int ty = threadIdx.x >> 6;
#pragma unroll
    for (int i = 0; i < 64; i += 4) {
      int d = bd + ty + i;
      int k = bk + tx;
      t[ty + i][tx] = (k < BANK_N) ? keys[(size_t)d * BANK_N + k] : 0.f;
    }
    __syncthreads();
#pragma unroll
    for (int i = 0; i < 64; i += 4) {
      int r = ty + i;
      kT[(size_t)(bk + r) * D_KEY + bd + tx] = f2bf(t[tx][r]);
    }
    return;
  }
  // vm8: fp8 cast, 4 elems/thread
  const int NV = BANK_P / 4;                       // 2432
  int idx = (b - 1136) * 256 + threadIdx.x;
  if (idx >= M_PAD * NV) return;
  int m = idx / NV;
  int k4 = (idx - m * NV) * 4;
  float4 v = make_float4(0.f, 0.f, 0.f, 0.f);
  if (m == ONES_ROW) {
    v.x = (k4     < BANK_N) ? 1.f : 0.f;
    v.y = (k4 + 1 < BANK_N) ? 1.f : 0.f;
    v.z = (k4 + 2 < BANK_N) ? 1.f : 0.f;
    v.w = (k4 + 3 < BANK_N) ? 1.f : 0.f;
  } else {
    const float* src = nullptr;
    if (m < 1536)          src = values + (size_t)m * BANK_N;
    else if (m < ONES_ROW) src = masks + (size_t)(m - 1536) * BANK_N;
    if (src) {
      if (k4 + 3 < BANK_N) v = *(const float4*)(src + k4);
      else {
        if (k4     < BANK_N) v.x = src[k4];
        if (k4 + 1 < BANK_N) v.y = src[k4 + 1];
        if (k4 + 2 < BANK_N) v.z = src[k4 + 2];
        if (k4 + 3 < BANK_N) v.w = src[k4 + 3];
      }
    }
  }
  *(unsigned*)(vm8 + (size_t)m * BANK_P + k4) = pack_fp8x4(v.x, v.y, v.z, v.w);
}

// ---- QK GEMM (bf16 in): E8[n][k] = fp8(exp(qT[n][:].kT[k][:])); pad cols -> 0 ----
__global__ void gemm_qk(const u16* __restrict__ A, const u16* __restrict__ B,
                        u8* __restrict__ E8)
{
  __shared__ __align__(16) u16 sbuf[16384];
  u16* As = sbuf;
  u16* Bs = sbuf + 4096;

  const int tid  = threadIdx.x;
  const int wave = tid >> 6;
  const int lane = tid & 63;
  const int bn = blockIdx.x, bm = blockIdx.y;

  const u16* Abase = A + (size_t)bm * 128 * D_KEY;
  const u16* Bbase = B + (size_t)bn * 128 * D_KEY;

  const int r  = lane >> 2;
  const int c8 = (lane & 3) << 3;
  const int s0 = wave, s1 = wave + 4;

  f32x4 acc[4][4];
#pragma unroll
  for (int i = 0; i < 4; i++)
#pragma unroll
    for (int j = 0; j < 4; j++) acc[i][j] = (f32x4){0.f, 0.f, 0.f, 0.f};

  const int m_in = lane & 15;
  const int quad = lane >> 4;
  const int wm = (wave >> 1) * 64;
  const int wn = (wave & 1) * 64;

  for (int kt = 0; kt < D_KEY; kt += 32) {
    load_lds16(Abase + (size_t)(s0 * 16 + r) * D_KEY + kt + c8, &As[s0 * 512]);
    load_lds16(Abase + (size_t)(s1 * 16 + r) * D_KEY + kt + c8, &As[s1 * 512]);
    load_lds16(Bbase + (size_t)(s0 * 16 + r) * D_KEY + kt + c8, &Bs[s0 * 512]);
    load_lds16(Bbase + (size_t)(s1 * 16 + r) * D_KEY + kt + c8, &Bs[s1 * 512]);
    __syncthreads();

    bf16x8 af[4], bfr[4];
#pragma unroll
    for (int i = 0; i < 4; i++)
      af[i] = *(const bf16x8*)&As[(wm + i * 16 + m_in) * 32 + quad * 8];
#pragma unroll
    for (int j = 0; j < 4; j++)
      bfr[j] = *(const bf16x8*)&Bs[(wn + j * 16 + m_in) * 32 + quad * 8];
#pragma unroll
    for (int i = 0; i < 4; i++)
#pragma unroll
      for (int j = 0; j < 4; j++)
        acc[i][j] = __builtin_amdgcn_mfma_f32_16x16x32_bf16(af[i], bfr[j], acc[i][j], 0, 0, 0);
    __syncthreads();
  }

  // exp -> fp8, zero pad cols; stage 16KB in LDS; coalesced store
  u8* sb8 = (u8*)sbuf;
#pragma unroll
  for (int i = 0; i < 4; i++)
#pragma unroll
    for (int j = 0; j < 4; j++)
#pragma unroll
      for (int t = 0; t < 4; t++) {
        int row_l = wm + i * 16 + quad * 4 + t;   // D layout: col=lane&15, row=quad*4+t [m89]
        int col_l = wn + j * 16 + m_in;
        bool valid = (bn * 128 + col_l) < BANK_N;
        sb8[(row_l << 7) + col_l] = valid ? f2fp8(__expf(acc[i][j][t])) : (u8)0;
      }
  __syncthreads();

  for (int chunk = tid; chunk < 1024; chunk += 256) {
    int row = chunk >> 3;
    int cu  = (chunk & 7) << 4;
    u32x4 v = *(const u32x4*)&sb8[(row << 7) + cu];
    *(u32x4*)&E8[(size_t)(bm * 128 + row) * BANK_P + bn * 128 + cu] = v;
  }
}

// ---- PV GEMM (fp8 in): memC[bz][m][n] = sum_k vm8[m][k]*E8[n][k], bf16 partials ----
__global__ void gemm_pv(const u8* __restrict__ A, const u8* __restrict__ B,
                        u16* __restrict__ memC, int kChunk, size_t cPartStride)
{
  __shared__ __align__(16) u16 sbuf[16384];   // fp8 tiles: As8 4K + Bs8 4K; C-stage 32K alias
  u8* As8 = (u8*)sbuf;
  u8* Bs8 = (u8*)sbuf + 4096;

  const int tid  = threadIdx.x;
  const int wave = tid >> 6;
  const int lane = tid & 63;

  int b = blockIdx.x;
  int bz = b / 169;                           // R4 decode (measured-fast)
  int rr = b - bz * 169;
  int gid = rr / 52;
  int rem = rr - gid * 52;
  int width = (gid < 3) ? 4 : 1;
  int bm = rem / width;
  int bn = gid * 4 + (rem - bm * width);

  const int kbeg = bz * kChunk;
  const int kend = kbeg + kChunk;

  const u8* Abase = A + (size_t)bm * 128 * BANK_P;
  const u8* Bbase = B + (size_t)bn * 128 * BANK_P;

  // staging: lane covers row = 32*wave + (lane>>1), 16B half = (lane&1)*16
  const int srow  = lane >> 1;
  const int shalf = (lane & 1) << 4;

  f32x4 acc[4][4];
#pragma unroll
  for (int i = 0; i < 4; i++)
#pragma unroll
    for (int j = 0; j < 4; j++) acc[i][j] = (f32x4){0.f, 0.f, 0.f, 0.f};

  const int m_in = lane & 15;
  const int quad = lane >> 4;
  const int wm = (wave >> 1) * 64;
  const int wn = (wave & 1) * 64;

  for (int kt = kbeg; kt < kend; kt += 32) {
    load_lds16(Abase + (size_t)(wave * 32 + srow) * BANK_P + kt + shalf, As8 + wave * 1024);
    load_lds16(Bbase + (size_t)(wave * 32 + srow) * BANK_P + kt + shalf, Bs8 + wave * 1024);
    __syncthreads();

    long af[4], bfr[4];
#pragma unroll
    for (int i = 0; i < 4; i++)
      af[i] = *(const long*)&As8[(wm + i * 16 + m_in) * 32 + quad * 8];
#pragma unroll
    for (int j = 0; j < 4; j++)
      bfr[j] = *(const long*)&Bs8[(wn + j * 16 + m_in) * 32 + quad * 8];
#pragma unroll
    for (int i = 0; i < 4; i++)
#pragma unroll
      for (int j = 0; j < 4; j++)
        acc[i][j] = __builtin_amdgcn_mfma_f32_16x16x32_fp8_fp8(af[i], bfr[j], acc[i][j], 0, 0, 0);
    __syncthreads();
  }

  // C-stage in LDS (bf16), coalesced NT store
#pragma unroll
  for (int i = 0; i < 4; i++)
#pragma unroll
    for (int j = 0; j < 4; j++)
#pragma unroll
      for (int t = 0; t < 4; t++) {
        int row_l = wm + i * 16 + quad * 4 + t;
        int col_l = wn + j * 16 + m_in;
        sbuf[(row_l << 7) + col_l] = f2bf(acc[i][j][t]);
      }
  __syncthreads();

  u16* Cg = memC + (size_t)bz * cPartStride;
  for (int chunk = tid; chunk < 2048; chunk += 256) {
    int row = chunk >> 4;
    int cu  = (chunk & 15) << 3;
    u32x4 v = *(const u32x4*)&sbuf[(row << 7) + cu];
    __builtin_nontemporal_store(v, (u32x4*)&Cg[(size_t)(bm * 128 + row) * LDCOL + bn * 128 + cu]);
  }
}

// ---- epilogue: vec4 over n; lsum from memC row ONES_ROW ----
__global__ void epilogue(const u16* __restrict__ memC, const float* __restrict__ q_out,
                         float* __restrict__ out, int nParts) {
  const int NV = N_TOK / 4;                     // 405
  int idx = blockIdx.x * 256 + threadIdx.x;
  if (idx >= OBJ_N * 1024 * NV) return;
  int n4 = (idx % NV) * 4;
  int t = idx / NV;
  int c = t & 1023;
  int o = t >> 10;
  const size_t ps = (size_t)M_PAD * LDCOL;

  const u16* lbase = memC + (size_t)ONES_ROW * LDCOL + n4;
  float4 l = make_float4(0.f, 0.f, 0.f, 0.f);
  for (int z = 0; z < nParts; z++) {
    ushort4 v = *(const ushort4*)(lbase + z * ps);
    l.x += bf2f(v.x); l.y += bf2f(v.y); l.z += bf2f(v.z); l.w += bf2f(v.w);
  }

  size_t rowoff = (c < 512) ? (size_t)(o * 512 + c) * LDCOL
                            : (size_t)(1536 + o) * LDCOL;
  const u16* base = memC + rowoff + n4;
  float4 s = make_float4(0.f, 0.f, 0.f, 0.f);
  for (int z = 0; z < nParts; z++) {
    ushort4 v = *(const ushort4*)(base + z * ps);
    s.x += bf2f(v.x); s.y += bf2f(v.y); s.z += bf2f(v.z); s.w += bf2f(v.w);
  }
  float4 rv;
  float ix = 1.f / l.x, iy = 1.f / l.y, iz = 1.f / l.z, iw = 1.f / l.w;
  if (c < 512) {
    rv.x = s.x * ix; rv.y = s.y * iy; rv.z = s.z * iz; rv.w = s.w * iw;
  } else {
    float4 q = *(const float4*)(q_out + (size_t)(o * 512 + (c - 512)) * N_TOK + n4);
    rv.x = q.x * s.x * ix; rv.y = q.y * s.y * iy;
    rv.z = q.z * s.z * iz; rv.w = q.w * s.w * iw;
  }
  *(float4*)(out + (size_t)(o * 1024 + c) * N_TOK + n4) = rv;
}

extern "C" void kernel_launch(void* const* d_in, const int* in_sizes, int n_in,
                              void* d_out, int out_size, void* d_ws, size_t ws_size,
                              hipStream_t stream) {
  const float* keys   = (const float*)d_in[0];
  const float* q_in   = (const float*)d_in[1];
  const float* q_out  = (const float*)d_in[2];
  const float* values = (const float*)d_in[3];
  const float* masks  = (const float*)d_in[4];
  float* out = (float*)d_out;

  char* ws = (char*)d_ws;
  size_t off = 0;
  auto alloc = [&](size_t bytes) -> void* {
    void* p = ws + off; off += (bytes + 255) & ~(size_t)255; return p;
  };
  u16* qT  = (u16*)alloc((size_t)N_PAD * D_KEY * 2);
  u16* kT  = (u16*)alloc((size_t)BANK_P * D_KEY * 2);
  u8*  vm8 = (u8*)alloc((size_t)M_PAD * BANK_P);
  u8*  E8  = (u8*)alloc((size_t)N_PAD * BANK_P);

  int nParts = 8;
  while (nParts > 1 && off + (size_t)nParts * M_PAD * LDCOL * 2 > ws_size) nParts >>= 1;
  u16* memC = (u16*)alloc((size_t)nParts * M_PAD * LDCOL * 2);

  const int vmBlocks = (M_PAD * (BANK_P / 4) + 255) / 256;   // 15808
  prep<<<1136 + vmBlocks, 256, 0, stream>>>(q_in, keys, values, masks, qT, kT, vm8);

  gemm_qk<<<dim3(BANK_P / 128, N_PAD / 128), 256, 0, stream>>>(qT, kT, E8);

  int kChunk = BANK_P / nParts;
  gemm_pv<<<dim3(169 * nParts), 256, 0, stream>>>(vm8, E8, memC, kChunk, (size_t)M_PAD * LDCOL);

  epilogue<<<(OBJ_N * 1024 * (N_TOK / 4) + 255) / 256, 256, 0, stream>>>(
      memC, q_out, out, nParts);
}

// Round 8
// 228.829 us; speedup vs baseline: 1.2175x; 1.0023x over previous
//
#include <hip/hip_runtime.h>
#include <hip/hip_bf16.h>

typedef unsigned short u16;
typedef unsigned char  u8;

#define D_KEY   128
#define BANK_N  9720
#define BANK_P  9728   /* 76*128 */
#define N_TOK   1620
#define N_PAD   1664   /* 13*128 */
#define OBJ_N   3
#define M_PAD   1664
#define LDCOL   1664
#define ONES_ROW 1539  /* vm row of 1.0 -> PV computes lsum as C row 1539 */
#define QK_SCALE 0.08838834764831845f

typedef __bf16 bf16x8 __attribute__((ext_vector_type(8)));
typedef float  f32x4  __attribute__((ext_vector_type(4)));
typedef unsigned int u32x4 __attribute__((ext_vector_type(4)));

__device__ __forceinline__ float bf2f(u16 u) {
  union { unsigned int i; float f; } v; v.i = ((unsigned int)u) << 16; return v.f;
}
__device__ __forceinline__ u16 f2bf(float f) {
  unsigned int x = __float_as_uint(f);
  unsigned int r = x + 0x7fffu + ((x >> 16) & 1u);  // RNE
  return (u16)(r >> 16);
}
__device__ __forceinline__ unsigned pack_fp8x4(float a, float b, float c, float d) {
  unsigned v = __builtin_amdgcn_cvt_pk_fp8_f32(a, b, 0, false);
  v = __builtin_amdgcn_cvt_pk_fp8_f32(c, d, v, true);
  return v;
}
__device__ __forceinline__ u8 f2fp8(float a) {
  return (u8)(__builtin_amdgcn_cvt_pk_fp8_f32(a, 0.f, 0, false) & 0xff);
}

__device__ __forceinline__ void load_lds16(const void* g, void* l) {
  __builtin_amdgcn_global_load_lds(
      (const __attribute__((address_space(1))) void*)g,
      (__attribute__((address_space(3))) void*)l, 16, 0, 0);
}

// ---- prep: qT cast (blocks 0..831) + keys transpose (832..1135) ----
__global__ void prep(const float* __restrict__ q, const float* __restrict__ keys,
                     u16* __restrict__ qT, u16* __restrict__ kT) {
  __shared__ float t[64][65];
  int b = blockIdx.x;
  if (b < 832) {                                   // qT: N_PAD*128 elems
    int idx = b * 256 + threadIdx.x;
    int n = idx >> 7, d = idx & 127;
    float v = (n < N_TOK) ? q[d * N_TOK + n] * QK_SCALE : 0.f;
    qT[idx] = f2bf(v);
    return;
  }
  b -= 832;                                        // keys transpose: 152 x 2 tiles
  const int bk = (b % 152) * 64;
  const int bd = (b / 152) * 64;
  const int tx = threadIdx.x & 63;
  const int ty = threadIdx.x >> 6;
#pragma unroll
  for (int i = 0; i < 64; i += 4) {
    int d = bd + ty + i;
    int k = bk + tx;
    t[ty + i][tx] = (k < BANK_N) ? keys[(size_t)d * BANK_N + k] : 0.f;
  }
  __syncthreads();
#pragma unroll
  for (int i = 0; i < 64; i += 4) {
    int r = ty + i;
    kT[(size_t)(bk + r) * D_KEY + bd + tx] = f2bf(t[tx][r]);
  }
}

// ---- QK GEMM (blocks 0..987) + vm8 fp8 cast (blocks 988..): one dispatch, overlapped ----
__global__ void gemm_qk(const u16* __restrict__ A, const u16* __restrict__ B,
                        u8* __restrict__ E8,
                        const float* __restrict__ values, const float* __restrict__ masks,
                        u8* __restrict__ vm8)
{
  __shared__ __align__(16) u16 sbuf[16384];

  int blk = blockIdx.x;
  const int tid = threadIdx.x;

  if (blk >= 988) {                                // vm8 cast: 4 elems/thread
    const int NV = BANK_P / 4;                     // 2432
    int idx = (blk - 988) * 256 + tid;
    if (idx >= M_PAD * NV) return;
    int m = idx / NV;
    int k4 = (idx - m * NV) * 4;
    float4 v = make_float4(0.f, 0.f, 0.f, 0.f);
    if (m == ONES_ROW) {
      v.x = (k4     < BANK_N) ? 1.f : 0.f;
      v.y = (k4 + 1 < BANK_N) ? 1.f : 0.f;
      v.z = (k4 + 2 < BANK_N) ? 1.f : 0.f;
      v.w = (k4 + 3 < BANK_N) ? 1.f : 0.f;
    } else {
      const float* src = nullptr;
      if (m < 1536)          src = values + (size_t)m * BANK_N;
      else if (m < ONES_ROW) src = masks + (size_t)(m - 1536) * BANK_N;
      if (src) {
        if (k4 + 3 < BANK_N) v = *(const float4*)(src + k4);
        else {
          if (k4     < BANK_N) v.x = src[k4];
          if (k4 + 1 < BANK_N) v.y = src[k4 + 1];
          if (k4 + 2 < BANK_N) v.z = src[k4 + 2];
          if (k4 + 3 < BANK_N) v.w = src[k4 + 3];
        }
      }
    }
    *(unsigned*)(vm8 + (size_t)m * BANK_P + k4) = pack_fp8x4(v.x, v.y, v.z, v.w);
    return;
  }

  // ---- QK tile ----
  u16* As = sbuf;
  u16* Bs = sbuf + 4096;
  const int wave = tid >> 6;
  const int lane = tid & 63;
  const int bn = blk % 76, bm = blk / 76;

  const u16* Abase = A + (size_t)bm * 128 * D_KEY;
  const u16* Bbase = B + (size_t)bn * 128 * D_KEY;

  const int r  = lane >> 2;
  const int c8 = (lane & 3) << 3;
  const int s0 = wave, s1 = wave + 4;

  f32x4 acc[4][4];
#pragma unroll
  for (int i = 0; i < 4; i++)
#pragma unroll
    for (int j = 0; j < 4; j++) acc[i][j] = (f32x4){0.f, 0.f, 0.f, 0.f};

  const int m_in = lane & 15;
  const int quad = lane >> 4;
  const int wm = (wave >> 1) * 64;
  const int wn = (wave & 1) * 64;

  for (int kt = 0; kt < D_KEY; kt += 32) {
    load_lds16(Abase + (size_t)(s0 * 16 + r) * D_KEY + kt + c8, &As[s0 * 512]);
    load_lds16(Abase + (size_t)(s1 * 16 + r) * D_KEY + kt + c8, &As[s1 * 512]);
    load_lds16(Bbase + (size_t)(s0 * 16 + r) * D_KEY + kt + c8, &Bs[s0 * 512]);
    load_lds16(Bbase + (size_t)(s1 * 16 + r) * D_KEY + kt + c8, &Bs[s1 * 512]);
    __syncthreads();

    bf16x8 af[4], bfr[4];
#pragma unroll
    for (int i = 0; i < 4; i++)
      af[i] = *(const bf16x8*)&As[(wm + i * 16 + m_in) * 32 + quad * 8];
#pragma unroll
    for (int j = 0; j < 4; j++)
      bfr[j] = *(const bf16x8*)&Bs[(wn + j * 16 + m_in) * 32 + quad * 8];
#pragma unroll
    for (int i = 0; i < 4; i++)
#pragma unroll
      for (int j = 0; j < 4; j++)
        acc[i][j] = __builtin_amdgcn_mfma_f32_16x16x32_bf16(af[i], bfr[j], acc[i][j], 0, 0, 0);
    __syncthreads();
  }

  // exp -> fp8, zero pad cols; stage 16KB in LDS; coalesced store
  u8* sb8 = (u8*)sbuf;
#pragma unroll
  for (int i = 0; i < 4; i++)
#pragma unroll
    for (int j = 0; j < 4; j++)
#pragma unroll
      for (int t = 0; t < 4; t++) {
        int row_l = wm + i * 16 + quad * 4 + t;   // D layout: col=lane&15, row=quad*4+t [m89]
        int col_l = wn + j * 16 + m_in;
        bool valid = (bn * 128 + col_l) < BANK_N;
        sb8[(row_l << 7) + col_l] = valid ? f2fp8(__expf(acc[i][j][t])) : (u8)0;
      }
  __syncthreads();

  for (int chunk = tid; chunk < 1024; chunk += 256) {
    int row = chunk >> 3;
    int cu  = (chunk & 7) << 4;
    u32x4 v = *(const u32x4*)&sb8[(row << 7) + cu];
    *(u32x4*)&E8[(size_t)(bm * 128 + row) * BANK_P + bn * 128 + cu] = v;
  }
}

// ---- PV GEMM (fp8, XOR-swizzled LDS): memC[bz][m][n] = sum_k vm8[m][k]*E8[n][k] ----
// Swizzle: LDS row R holds its two 16B halves swapped iff (R>>2)&1. Staging lane l
// fetches global half (l&1)^((l>>3)&1); frag read XORs byte offset with ((m_in>>2)&1)<<4.
// Result: uniform 2 lanes/bank on ds_read_b64 (free, m136) vs 4-way before.
__global__ void gemm_pv(const u8* __restrict__ A, const u8* __restrict__ B,
                        u16* __restrict__ memC, int kChunk, size_t cPartStride)
{
  __shared__ __align__(16) u16 sbuf[16384];   // fp8 tiles: As8 4K + Bs8 4K; C-stage 32K alias
  u8* As8 = (u8*)sbuf;
  u8* Bs8 = (u8*)sbuf + 4096;

  const int tid  = threadIdx.x;
  const int wave = tid >> 6;
  const int lane = tid & 63;

  int b = blockIdx.x;
  int bz = b / 169;
  int rr = b - bz * 169;
  int gid = rr / 52;
  int rem = rr - gid * 52;
  int width = (gid < 3) ? 4 : 1;
  int bm = rem / width;
  int bn = gid * 4 + (rem - bm * width);

  const int kbeg = bz * kChunk;
  const int kend = kbeg + kChunk;

  const u8* Abase = A + (size_t)bm * 128 * BANK_P;
  const u8* Bbase = B + (size_t)bn * 128 * BANK_P;

  // staging: lane covers row = 32*wave + (lane>>1); source 16B half XOR-swizzled
  const int srow  = lane >> 1;
  const int shalf = (((lane & 1) ^ ((lane >> 3) & 1)) << 4);

  f32x4 acc[4][4];
#pragma unroll
  for (int i = 0; i < 4; i++)
#pragma unroll
    for (int j = 0; j < 4; j++) acc[i][j] = (f32x4){0.f, 0.f, 0.f, 0.f};

  const int m_in = lane & 15;
  const int quad = lane >> 4;
  const int wm = (wave >> 1) * 64;
  const int wn = (wave & 1) * 64;
  const int fxor = ((m_in >> 2) & 1) << 4;    // un-swizzle for frag read

  for (int kt = kbeg; kt < kend; kt += 32) {
    load_lds16(Abase + (size_t)(wave * 32 + srow) * BANK_P + kt + shalf, As8 + wave * 1024);
    load_lds16(Bbase + (size_t)(wave * 32 + srow) * BANK_P + kt + shalf, Bs8 + wave * 1024);
    __syncthreads();

    long af[4], bfr[4];
#pragma unroll
    for (int i = 0; i < 4; i++)
      af[i] = *(const long*)&As8[(wm + i * 16 + m_in) * 32 + (quad * 8 ^ fxor)];
#pragma unroll
    for (int j = 0; j < 4; j++)
      bfr[j] = *(const long*)&Bs8[(wn + j * 16 + m_in) * 32 + (quad * 8 ^ fxor)];
#pragma unroll
    for (int i = 0; i < 4; i++)
#pragma unroll
      for (int j = 0; j < 4; j++)
        acc[i][j] = __builtin_amdgcn_mfma_f32_16x16x32_fp8_fp8(af[i], bfr[j], acc[i][j], 0, 0, 0);
    __syncthreads();
  }

  // C-stage in LDS (bf16), coalesced NT store
#pragma unroll
  for (int i = 0; i < 4; i++)
#pragma unroll
    for (int j = 0; j < 4; j++)
#pragma unroll
      for (int t = 0; t < 4; t++) {
        int row_l = wm + i * 16 + quad * 4 + t;
        int col_l = wn + j * 16 + m_in;
        sbuf[(row_l << 7) + col_l] = f2bf(acc[i][j][t]);
      }
  __syncthreads();

  u16* Cg = memC + (size_t)bz * cPartStride;
  for (int chunk = tid; chunk < 2048; chunk += 256) {
    int row = chunk >> 4;
    int cu  = (chunk & 15) << 3;
    u32x4 v = *(const u32x4*)&sbuf[(row << 7) + cu];
    __builtin_nontemporal_store(v, (u32x4*)&Cg[(size_t)(bm * 128 + row) * LDCOL + bn * 128 + cu]);
  }
}

// ---- epilogue: vec4 over n; lsum from memC row ONES_ROW ----
__global__ void epilogue(const u16* __restrict__ memC, const float* __restrict__ q_out,
                         float* __restrict__ out, int nParts) {
  const int NV = N_TOK / 4;                     // 405
  int idx = blockIdx.x * 256 + threadIdx.x;
  if (idx >= OBJ_N * 1024 * NV) return;
  int n4 = (idx % NV) * 4;
  int t = idx / NV;
  int c = t & 1023;
  int o = t >> 10;
  const size_t ps = (size_t)M_PAD * LDCOL;

  const u16* lbase = memC + (size_t)ONES_ROW * LDCOL + n4;
  float4 l = make_float4(0.f, 0.f, 0.f, 0.f);
  for (int z = 0; z < nParts; z++) {
    ushort4 v = *(const ushort4*)(lbase + z * ps);
    l.x += bf2f(v.x); l.y += bf2f(v.y); l.z += bf2f(v.z); l.w += bf2f(v.w);
  }

  size_t rowoff = (c < 512) ? (size_t)(o * 512 + c) * LDCOL
                            : (size_t)(1536 + o) * LDCOL;
  const u16* base = memC + rowoff + n4;
  float4 s = make_float4(0.f, 0.f, 0.f, 0.f);
  for (int z = 0; z < nParts; z++) {
    ushort4 v = *(const ushort4*)(base + z * ps);
    s.x += bf2f(v.x); s.y += bf2f(v.y); s.z += bf2f(v.z); s.w += bf2f(v.w);
  }
  float4 rv;
  float ix = 1.f / l.x, iy = 1.f / l.y, iz = 1.f / l.z, iw = 1.f / l.w;
  if (c < 512) {
    rv.x = s.x * ix; rv.y = s.y * iy; rv.z = s.z * iz; rv.w = s.w * iw;
  } else {
    float4 q = *(const float4*)(q_out + (size_t)(o * 512 + (c - 512)) * N_TOK + n4);
    rv.x = q.x * s.x * ix; rv.y = q.y * s.y * iy;
    rv.z = q.z * s.z * iz; rv.w = q.w * s.w * iw;
  }
  *(float4*)(out + (size_t)(o * 1024 + c) * N_TOK + n4) = rv;
}

extern "C" void kernel_launch(void* const* d_in, const int* in_sizes, int n_in,
                              void* d_out, int out_size, void* d_ws, size_t ws_size,
                              hipStream_t stream) {
  const float* keys   = (const float*)d_in[0];
  const float* q_in   = (const float*)d_in[1];
  const float* q_out  = (const float*)d_in[2];
  const float* values = (const float*)d_in[3];
  const float* masks  = (const float*)d_in[4];
  float* out = (float*)d_out;

  char* ws = (char*)d_ws;
  size_t off = 0;
  auto alloc = [&](size_t bytes) -> void* {
    void* p = ws + off; off += (bytes + 255) & ~(size_t)255; return p;
  };
  u16* qT  = (u16*)alloc((size_t)N_PAD * D_KEY * 2);
  u16* kT  = (u16*)alloc((size_t)BANK_P * D_KEY * 2);
  u8*  vm8 = (u8*)alloc((size_t)M_PAD * BANK_P);
  u8*  E8  = (u8*)alloc((size_t)N_PAD * BANK_P);

  int nParts = 8;
  while (nParts > 1 && off + (size_t)nParts * M_PAD * LDCOL * 2 > ws_size) nParts >>= 1;
  u16* memC = (u16*)alloc((size_t)nParts * M_PAD * LDCOL * 2);

  prep<<<1136, 256, 0, stream>>>(q_in, keys, qT, kT);

  const int vmBlocks = (M_PAD * (BANK_P / 4) + 255) / 256;   // 15808
  gemm_qk<<<988 + vmBlocks, 256, 0, stream>>>(qT, kT, E8, values, masks, vm8);

  int kChunk = BANK_P / nParts;
  gemm_pv<<<dim3(169 * nParts), 256, 0, stream>>>(vm8, E8, memC, kChunk, (size_t)M_PAD * LDCOL);

  epilogue<<<(OBJ_N * 1024 * (N_TOK / 4) + 255) / 256, 256, 0, stream>>>(
      memC, q_out, out, nParts);
}

// Round 9
// 207.435 us; speedup vs baseline: 1.3430x; 1.1031x over previous
//
#include <hip/hip_runtime.h>
#include <hip/hip_bf16.h>

typedef unsigned short u16;
typedef unsigned char  u8;

#define D_KEY   128
#define BANK_N  9720
#define BANK_P  9728   /* 76*128 */
#define N_TOK   1620
#define N_PAD   1664   /* 13*128 */
#define OBJ_N   3
#define M_PAD   1664
#define LDCOL   1664
#define ONES_ROW 1539  /* vm row of 1.0 -> PV computes lsum as C row 1539 */
#define QK_SCALE 0.08838834764831845f

typedef __bf16 bf16x8 __attribute__((ext_vector_type(8)));
typedef float  f32x4  __attribute__((ext_vector_type(4)));
typedef unsigned int u32x4 __attribute__((ext_vector_type(4)));

__device__ __forceinline__ float bf2f(u16 u) {
  union { unsigned int i; float f; } v; v.i = ((unsigned int)u) << 16; return v.f;
}
__device__ __forceinline__ u16 f2bf(float f) {
  unsigned int x = __float_as_uint(f);
  unsigned int r = x + 0x7fffu + ((x >> 16) & 1u);  // RNE
  return (u16)(r >> 16);
}
__device__ __forceinline__ unsigned pack_fp8x4(float a, float b, float c, float d) {
  unsigned v = __builtin_amdgcn_cvt_pk_fp8_f32(a, b, 0, false);
  v = __builtin_amdgcn_cvt_pk_fp8_f32(c, d, v, true);
  return v;
}
__device__ __forceinline__ u8 f2fp8(float a) {
  return (u8)(__builtin_amdgcn_cvt_pk_fp8_f32(a, 0.f, 0, false) & 0xff);
}

__device__ __forceinline__ void load_lds16(const void* g, void* l) {
  __builtin_amdgcn_global_load_lds(
      (const __attribute__((address_space(1))) void*)g,
      (__attribute__((address_space(3))) void*)l, 16, 0, 0);
}

// ---- prep: qT cast (0..831) + keys transpose (832..1135) + vm8 fp8 cast (1136..) ----
__global__ void prep(const float* __restrict__ q, const float* __restrict__ keys,
                     const float* __restrict__ values, const float* __restrict__ masks,
                     u16* __restrict__ qT, u16* __restrict__ kT, u8* __restrict__ vm8) {
  __shared__ float t[64][65];
  int b = blockIdx.x;
  if (b < 832) {                                   // qT: N_PAD*128 elems
    int idx = b * 256 + threadIdx.x;
    int n = idx >> 7, d = idx & 127;
    float v = (n < N_TOK) ? q[d * N_TOK + n] * QK_SCALE : 0.f;
    qT[idx] = f2bf(v);
    return;
  }
  if (b < 1136) {                                  // keys transpose: 152 x 2 tiles
    b -= 832;
    const int bk = (b % 152) * 64;
    const int bd = (b / 152) * 64;
    const int tx = threadIdx.x & 63;
    const int ty = threadIdx.x >> 6;
#pragma unroll
    for (int i = 0; i < 64; i += 4) {
      int d = bd + ty + i;
      int k = bk + tx;
      t[ty + i][tx] = (k < BANK_N) ? keys[(size_t)d * BANK_N + k] : 0.f;
    }
    __syncthreads();
#pragma unroll
    for (int i = 0; i < 64; i += 4) {
      int r = ty + i;
      kT[(size_t)(bk + r) * D_KEY + bd + tx] = f2bf(t[tx][r]);
    }
    return;
  }
  // vm8: fp8 cast, 4 elems/thread
  const int NV = BANK_P / 4;                       // 2432
  int idx = (b - 1136) * 256 + threadIdx.x;
  if (idx >= M_PAD * NV) return;
  int m = idx / NV;
  int k4 = (idx - m * NV) * 4;
  float4 v = make_float4(0.f, 0.f, 0.f, 0.f);
  if (m == ONES_ROW) {
    v.x = (k4     < BANK_N) ? 1.f : 0.f;
    v.y = (k4 + 1 < BANK_N) ? 1.f : 0.f;
    v.z = (k4 + 2 < BANK_N) ? 1.f : 0.f;
    v.w = (k4 + 3 < BANK_N) ? 1.f : 0.f;
  } else {
    const float* src = nullptr;
    if (m < 1536)          src = values + (size_t)m * BANK_N;
    else if (m < ONES_ROW) src = masks + (size_t)(m - 1536) * BANK_N;
    if (src) {
      if (k4 + 3 < BANK_N) v = *(const float4*)(src + k4);
      else {
        if (k4     < BANK_N) v.x = src[k4];
        if (k4 + 1 < BANK_N) v.y = src[k4 + 1];
        if (k4 + 2 < BANK_N) v.z = src[k4 + 2];
        if (k4 + 3 < BANK_N) v.w = src[k4 + 3];
      }
    }
  }
  *(unsigned*)(vm8 + (size_t)m * BANK_P + k4) = pack_fp8x4(v.x, v.y, v.z, v.w);
}

// ---- QK GEMM (bf16 in, 16 KB LDS): E8[n][k] = fp8(exp(qT.kT)); pad cols -> 0 ----
__global__ void gemm_qk(const u16* __restrict__ A, const u16* __restrict__ B,
                        u8* __restrict__ E8)
{
  __shared__ __align__(16) u16 sbuf[8192];    // 16 KB: As 8K + Bs 8K; E8-stage aliases all
  u16* As = sbuf;
  u16* Bs = sbuf + 4096;

  const int tid  = threadIdx.x;
  const int wave = tid >> 6;
  const int lane = tid & 63;
  const int bn = blockIdx.x % 76, bm = blockIdx.x / 76;

  const u16* Abase = A + (size_t)bm * 128 * D_KEY;
  const u16* Bbase = B + (size_t)bn * 128 * D_KEY;

  const int r  = lane >> 2;
  const int c8 = (lane & 3) << 3;
  const int s0 = wave, s1 = wave + 4;

  f32x4 acc[4][4];
#pragma unroll
  for (int i = 0; i < 4; i++)
#pragma unroll
    for (int j = 0; j < 4; j++) acc[i][j] = (f32x4){0.f, 0.f, 0.f, 0.f};

  const int m_in = lane & 15;
  const int quad = lane >> 4;
  const int wm = (wave >> 1) * 64;
  const int wn = (wave & 1) * 64;

  for (int kt = 0; kt < D_KEY; kt += 32) {
    load_lds16(Abase + (size_t)(s0 * 16 + r) * D_KEY + kt + c8, &As[s0 * 512]);
    load_lds16(Abase + (size_t)(s1 * 16 + r) * D_KEY + kt + c8, &As[s1 * 512]);
    load_lds16(Bbase + (size_t)(s0 * 16 + r) * D_KEY + kt + c8, &Bs[s0 * 512]);
    load_lds16(Bbase + (size_t)(s1 * 16 + r) * D_KEY + kt + c8, &Bs[s1 * 512]);
    __syncthreads();

    bf16x8 af[4], bfr[4];
#pragma unroll
    for (int i = 0; i < 4; i++)
      af[i] = *(const bf16x8*)&As[(wm + i * 16 + m_in) * 32 + quad * 8];
#pragma unroll
    for (int j = 0; j < 4; j++)
      bfr[j] = *(const bf16x8*)&Bs[(wn + j * 16 + m_in) * 32 + quad * 8];
#pragma unroll
    for (int i = 0; i < 4; i++)
#pragma unroll
      for (int j = 0; j < 4; j++)
        acc[i][j] = __builtin_amdgcn_mfma_f32_16x16x32_bf16(af[i], bfr[j], acc[i][j], 0, 0, 0);
    __syncthreads();
  }

  // exp -> fp8, zero pad cols; stage 16KB in LDS; coalesced store
  u8* sb8 = (u8*)sbuf;
#pragma unroll
  for (int i = 0; i < 4; i++)
#pragma unroll
    for (int j = 0; j < 4; j++)
#pragma unroll
      for (int t = 0; t < 4; t++) {
        int row_l = wm + i * 16 + quad * 4 + t;   // D layout: col=lane&15, row=quad*4+t [m89]
        int col_l = wn + j * 16 + m_in;
        bool valid = (bn * 128 + col_l) < BANK_N;
        sb8[(row_l << 7) + col_l] = valid ? f2fp8(__expf(acc[i][j][t])) : (u8)0;
      }
  __syncthreads();

  for (int chunk = tid; chunk < 1024; chunk += 256) {
    int row = chunk >> 3;
    int cu  = (chunk & 7) << 4;
    u32x4 v = *(const u32x4*)&sb8[(row << 7) + cu];
    *(u32x4*)&E8[(size_t)(bm * 128 + row) * BANK_P + bn * 128 + cu] = v;
  }
}

// ---- PV GEMM (fp8, XOR-swizzled LDS, 16 KB, half-C staging) ----
// Swizzle [R8-verified]: LDS row R's two 16B halves swapped iff (R>>2)&1; staging lane l
// fetches global half (l&1)^((l>>3)&1); frag read XORs byte offset with ((m_in>>2)&1)<<4.
// -> uniform 2 lanes/bank on ds_read_b64 (free, m136).
__global__ __launch_bounds__(256, 4)
void gemm_pv(const u8* __restrict__ A, const u8* __restrict__ B,
             u16* __restrict__ memC, int kChunk, size_t cPartStride)
{
  __shared__ __align__(16) u16 sbuf[8192];    // 16 KB: As8 4K + Bs8 4K; C-half-stage aliases
  u8* As8 = (u8*)sbuf;
  u8* Bs8 = (u8*)sbuf + 4096;

  const int tid  = threadIdx.x;
  const int wave = tid >> 6;
  const int lane = tid & 63;

  int b = blockIdx.x;
  int bz = b / 169;
  int rr = b - bz * 169;
  int gid = rr / 52;
  int rem = rr - gid * 52;
  int width = (gid < 3) ? 4 : 1;
  int bm = rem / width;
  int bn = gid * 4 + (rem - bm * width);

  const int kbeg = bz * kChunk;
  const int kend = kbeg + kChunk;

  const u8* Abase = A + (size_t)bm * 128 * BANK_P;
  const u8* Bbase = B + (size_t)bn * 128 * BANK_P;

  const int srow  = lane >> 1;
  const int shalf = (((lane & 1) ^ ((lane >> 3) & 1)) << 4);

  f32x4 acc[4][4];
#pragma unroll
  for (int i = 0; i < 4; i++)
#pragma unroll
    for (int j = 0; j < 4; j++) acc[i][j] = (f32x4){0.f, 0.f, 0.f, 0.f};

  const int m_in = lane & 15;
  const int quad = lane >> 4;
  const int wm = (wave >> 1) * 64;
  const int wn = (wave & 1) * 64;
  const int fxor = ((m_in >> 2) & 1) << 4;

  for (int kt = kbeg; kt < kend; kt += 32) {
    load_lds16(Abase + (size_t)(wave * 32 + srow) * BANK_P + kt + shalf, As8 + wave * 1024);
    load_lds16(Bbase + (size_t)(wave * 32 + srow) * BANK_P + kt + shalf, Bs8 + wave * 1024);
    __syncthreads();

    long af[4], bfr[4];
#pragma unroll
    for (int i = 0; i < 4; i++)
      af[i] = *(const long*)&As8[(wm + i * 16 + m_in) * 32 + (quad * 8 ^ fxor)];
#pragma unroll
    for (int j = 0; j < 4; j++)
      bfr[j] = *(const long*)&Bs8[(wn + j * 16 + m_in) * 32 + (quad * 8 ^ fxor)];
#pragma unroll
    for (int i = 0; i < 4; i++)
#pragma unroll
      for (int j = 0; j < 4; j++)
        acc[i][j] = __builtin_amdgcn_mfma_f32_16x16x32_fp8_fp8(af[i], bfr[j], acc[i][j], 0, 0, 0);
    __syncthreads();
  }

  // C-stage in two 16-KB halves (rows 0-63 by waves 0,1; rows 64-127 by waves 2,3)
  u16* Cg = memC + (size_t)bz * cPartStride;
#pragma unroll
  for (int h = 0; h < 2; h++) {
    __syncthreads();
    if ((wave >> 1) == h) {
#pragma unroll
      for (int i = 0; i < 4; i++)
#pragma unroll
        for (int j = 0; j < 4; j++)
#pragma unroll
          for (int t = 0; t < 4; t++) {
            int row_l = i * 16 + quad * 4 + t;      // row within half
            int col_l = wn + j * 16 + m_in;
            sbuf[(row_l << 7) + col_l] = f2bf(acc[i][j][t]);
          }
    }
    __syncthreads();
    for (int chunk = tid; chunk < 1024; chunk += 256) {
      int row = chunk >> 4;                         // 0..63
      int cu  = (chunk & 15) << 3;
      u32x4 v = *(const u32x4*)&sbuf[(row << 7) + cu];
      __builtin_nontemporal_store(
          v, (u32x4*)&Cg[(size_t)(bm * 128 + h * 64 + row) * LDCOL + bn * 128 + cu]);
    }
  }
}

// ---- epilogue: vec4 over n; lsum from memC row ONES_ROW ----
__global__ void epilogue(const u16* __restrict__ memC, const float* __restrict__ q_out,
                         float* __restrict__ out, int nParts) {
  const int NV = N_TOK / 4;                     // 405
  int idx = blockIdx.x * 256 + threadIdx.x;
  if (idx >= OBJ_N * 1024 * NV) return;
  int n4 = (idx % NV) * 4;
  int t = idx / NV;
  int c = t & 1023;
  int o = t >> 10;
  const size_t ps = (size_t)M_PAD * LDCOL;

  const u16* lbase = memC + (size_t)ONES_ROW * LDCOL + n4;
  float4 l = make_float4(0.f, 0.f, 0.f, 0.f);
  for (int z = 0; z < nParts; z++) {
    ushort4 v = *(const ushort4*)(lbase + z * ps);
    l.x += bf2f(v.x); l.y += bf2f(v.y); l.z += bf2f(v.z); l.w += bf2f(v.w);
  }

  size_t rowoff = (c < 512) ? (size_t)(o * 512 + c) * LDCOL
                            : (size_t)(1536 + o) * LDCOL;
  const u16* base = memC + rowoff + n4;
  float4 s = make_float4(0.f, 0.f, 0.f, 0.f);
  for (int z = 0; z < nParts; z++) {
    ushort4 v = *(const ushort4*)(base + z * ps);
    s.x += bf2f(v.x); s.y += bf2f(v.y); s.z += bf2f(v.z); s.w += bf2f(v.w);
  }
  float4 rv;
  float ix = 1.f / l.x, iy = 1.f / l.y, iz = 1.f / l.z, iw = 1.f / l.w;
  if (c < 512) {
    rv.x = s.x * ix; rv.y = s.y * iy; rv.z = s.z * iz; rv.w = s.w * iw;
  } else {
    float4 q = *(const float4*)(q_out + (size_t)(o * 512 + (c - 512)) * N_TOK + n4);
    rv.x = q.x * s.x * ix; rv.y = q.y * s.y * iy;
    rv.z = q.z * s.z * iz; rv.w = q.w * s.w * iw;
  }
  *(float4*)(out + (size_t)(o * 1024 + c) * N_TOK + n4) = rv;
}

extern "C" void kernel_launch(void* const* d_in, const int* in_sizes, int n_in,
                              void* d_out, int out_size, void* d_ws, size_t ws_size,
                              hipStream_t stream) {
  const float* keys   = (const float*)d_in[0];
  const float* q_in   = (const float*)d_in[1];
  const float* q_out  = (const float*)d_in[2];
  const float* values = (const float*)d_in[3];
  const float* masks  = (const float*)d_in[4];
  float* out = (float*)d_out;

  char* ws = (char*)d_ws;
  size_t off = 0;
  auto alloc = [&](size_t bytes) -> void* {
    void* p = ws + off; off += (bytes + 255) & ~(size_t)255; return p;
  };
  u16* qT  = (u16*)alloc((size_t)N_PAD * D_KEY * 2);
  u16* kT  = (u16*)alloc((size_t)BANK_P * D_KEY * 2);
  u8*  vm8 = (u8*)alloc((size_t)M_PAD * BANK_P);
  u8*  E8  = (u8*)alloc((size_t)N_PAD * BANK_P);

  int nParts = 4;
  while (nParts > 1 && off + (size_t)nParts * M_PAD * LDCOL * 2 > ws_size) nParts >>= 1;
  u16* memC = (u16*)alloc((size_t)nParts * M_PAD * LDCOL * 2);

  const int vmBlocks = (M_PAD * (BANK_P / 4) + 255) / 256;   // 15808
  prep<<<1136 + vmBlocks, 256, 0, stream>>>(q_in, keys, values, masks, qT, kT, vm8);

  gemm_qk<<<988, 256, 0, stream>>>(qT, kT, E8);

  int kChunk = BANK_P / nParts;
  gemm_pv<<<dim3(169 * nParts), 256, 0, stream>>>(vm8, E8, memC, kChunk, (size_t)M_PAD * LDCOL);

  epilogue<<<(OBJ_N * 1024 * (N_TOK / 4) + 255) / 256, 256, 0, stream>>>(
      memC, q_out, out, nParts);
}

// Round 10
// 192.208 us; speedup vs baseline: 1.4494x; 1.0792x over previous
//
#include <hip/hip_runtime.h>
#include <hip/hip_bf16.h>

typedef unsigned short u16;
typedef unsigned char  u8;

#define D_KEY   128
#define BANK_N  9720
#define BANK_P  9728   /* 76*128 */
#define N_TOK   1620
#define N_PAD   1664   /* 13*128 */
#define OBJ_N   3
#define M_PAD   1664
#define LDCOL   1664
#define ONES_ROW 1539  /* vm row of 1.0 -> PV computes lsum as C row 1539 */
#define QK_SCALE 0.08838834764831845f

typedef __bf16 bf16x8 __attribute__((ext_vector_type(8)));
typedef float  f32x4  __attribute__((ext_vector_type(4)));
typedef unsigned int u32x4 __attribute__((ext_vector_type(4)));
typedef int i32x8 __attribute__((ext_vector_type(8)));

__device__ __forceinline__ float bf2f(u16 u) {
  union { unsigned int i; float f; } v; v.i = ((unsigned int)u) << 16; return v.f;
}
__device__ __forceinline__ u16 f2bf(float f) {
  unsigned int x = __float_as_uint(f);
  unsigned int r = x + 0x7fffu + ((x >> 16) & 1u);  // RNE
  return (u16)(r >> 16);
}
__device__ __forceinline__ unsigned pack_fp8x4(float a, float b, float c, float d) {
  unsigned v = __builtin_amdgcn_cvt_pk_fp8_f32(a, b, 0, false);
  v = __builtin_amdgcn_cvt_pk_fp8_f32(c, d, v, true);
  return v;
}
__device__ __forceinline__ u8 f2fp8(float a) {
  return (u8)(__builtin_amdgcn_cvt_pk_fp8_f32(a, 0.f, 0, false) & 0xff);
}

__device__ __forceinline__ void load_lds16(const void* g, void* l) {
  __builtin_amdgcn_global_load_lds(
      (const __attribute__((address_space(1))) void*)g,
      (__attribute__((address_space(3))) void*)l, 16, 0, 0);
}

// ---- prep: qT cast (0..831) + keys transpose (832..1135) + vm8 fp8 cast (1136..) ----
__global__ void prep(const float* __restrict__ q, const float* __restrict__ keys,
                     const float* __restrict__ values, const float* __restrict__ masks,
                     u16* __restrict__ qT, u16* __restrict__ kT, u8* __restrict__ vm8) {
  __shared__ float t[64][65];
  int b = blockIdx.x;
  if (b < 832) {                                   // qT: N_PAD*128 elems
    int idx = b * 256 + threadIdx.x;
    int n = idx >> 7, d = idx & 127;
    float v = (n < N_TOK) ? q[d * N_TOK + n] * QK_SCALE : 0.f;
    qT[idx] = f2bf(v);
    return;
  }
  if (b < 1136) {                                  // keys transpose: 152 x 2 tiles
    b -= 832;
    const int bk = (b % 152) * 64;
    const int bd = (b / 152) * 64;
    const int tx = threadIdx.x & 63;
    const int ty = threadIdx.x >> 6;
#pragma unroll
    for (int i = 0; i < 64; i += 4) {
      int d = bd + ty + i;
      int k = bk + tx;
      t[ty + i][tx] = (k < BANK_N) ? keys[(size_t)d * BANK_N + k] : 0.f;
    }
    __syncthreads();
#pragma unroll
    for (int i = 0; i < 64; i += 4) {
      int r = ty + i;
      kT[(size_t)(bk + r) * D_KEY + bd + tx] = f2bf(t[tx][r]);
    }
    return;
  }
  // vm8: fp8 cast, 4 elems/thread
  const int NV = BANK_P / 4;                       // 2432
  int idx = (b - 1136) * 256 + threadIdx.x;
  if (idx >= M_PAD * NV) return;
  int m = idx / NV;
  int k4 = (idx - m * NV) * 4;
  float4 v = make_float4(0.f, 0.f, 0.f, 0.f);
  if (m == ONES_ROW) {
    v.x = (k4     < BANK_N) ? 1.f : 0.f;
    v.y = (k4 + 1 < BANK_N) ? 1.f : 0.f;
    v.z = (k4 + 2 < BANK_N) ? 1.f : 0.f;
    v.w = (k4 + 3 < BANK_N) ? 1.f : 0.f;
  } else {
    const float* src = nullptr;
    if (m < 1536)          src = values + (size_t)m * BANK_N;
    else if (m < ONES_ROW) src = masks + (size_t)(m - 1536) * BANK_N;
    if (src) {
      if (k4 + 3 < BANK_N) v = *(const float4*)(src + k4);
      else {
        if (k4     < BANK_N) v.x = src[k4];
        if (k4 + 1 < BANK_N) v.y = src[k4 + 1];
        if (k4 + 2 < BANK_N) v.z = src[k4 + 2];
        if (k4 + 3 < BANK_N) v.w = src[k4 + 3];
      }
    }
  }
  *(unsigned*)(vm8 + (size_t)m * BANK_P + k4) = pack_fp8x4(v.x, v.y, v.z, v.w);
}

// ---- QK GEMM (bf16 in, 16 KB LDS): E8[n][k] = fp8(exp(qT.kT)); pad cols -> 0 ----
__global__ void gemm_qk(const u16* __restrict__ A, const u16* __restrict__ B,
                        u8* __restrict__ E8)
{
  __shared__ __align__(16) u16 sbuf[8192];    // 16 KB: As 8K + Bs 8K; E8-stage aliases all
  u16* As = sbuf;
  u16* Bs = sbuf + 4096;

  const int tid  = threadIdx.x;
  const int wave = tid >> 6;
  const int lane = tid & 63;
  const int bn = blockIdx.x % 76, bm = blockIdx.x / 76;

  const u16* Abase = A + (size_t)bm * 128 * D_KEY;
  const u16* Bbase = B + (size_t)bn * 128 * D_KEY;

  const int r  = lane >> 2;
  const int c8 = (lane & 3) << 3;
  const int s0 = wave, s1 = wave + 4;

  f32x4 acc[4][4];
#pragma unroll
  for (int i = 0; i < 4; i++)
#pragma unroll
    for (int j = 0; j < 4; j++) acc[i][j] = (f32x4){0.f, 0.f, 0.f, 0.f};

  const int m_in = lane & 15;
  const int quad = lane >> 4;
  const int wm = (wave >> 1) * 64;
  const int wn = (wave & 1) * 64;

  for (int kt = 0; kt < D_KEY; kt += 32) {
    load_lds16(Abase + (size_t)(s0 * 16 + r) * D_KEY + kt + c8, &As[s0 * 512]);
    load_lds16(Abase + (size_t)(s1 * 16 + r) * D_KEY + kt + c8, &As[s1 * 512]);
    load_lds16(Bbase + (size_t)(s0 * 16 + r) * D_KEY + kt + c8, &Bs[s0 * 512]);
    load_lds16(Bbase + (size_t)(s1 * 16 + r) * D_KEY + kt + c8, &Bs[s1 * 512]);
    __syncthreads();

    bf16x8 af[4], bfr[4];
#pragma unroll
    for (int i = 0; i < 4; i++)
      af[i] = *(const bf16x8*)&As[(wm + i * 16 + m_in) * 32 + quad * 8];
#pragma unroll
    for (int j = 0; j < 4; j++)
      bfr[j] = *(const bf16x8*)&Bs[(wn + j * 16 + m_in) * 32 + quad * 8];
#pragma unroll
    for (int i = 0; i < 4; i++)
#pragma unroll
      for (int j = 0; j < 4; j++)
        acc[i][j] = __builtin_amdgcn_mfma_f32_16x16x32_bf16(af[i], bfr[j], acc[i][j], 0, 0, 0);
    __syncthreads();
  }

  // exp -> fp8, zero pad cols; stage 16KB in LDS; coalesced store
  u8* sb8 = (u8*)sbuf;
#pragma unroll
  for (int i = 0; i < 4; i++)
#pragma unroll
    for (int j = 0; j < 4; j++)
#pragma unroll
      for (int t = 0; t < 4; t++) {
        int row_l = wm + i * 16 + quad * 4 + t;   // D layout: col=lane&15, row=quad*4+t [m89]
        int col_l = wn + j * 16 + m_in;
        bool valid = (bn * 128 + col_l) < BANK_N;
        sb8[(row_l << 7) + col_l] = valid ? f2fp8(__expf(acc[i][j][t])) : (u8)0;
      }
  __syncthreads();

  for (int chunk = tid; chunk < 1024; chunk += 256) {
    int row = chunk >> 3;
    int cu  = (chunk & 7) << 4;
    u32x4 v = *(const u32x4*)&sb8[(row << 7) + cu];
    *(u32x4*)&E8[(size_t)(bm * 128 + row) * BANK_P + bn * 128 + cu] = v;
  }
}

// ---- PV GEMM: MX-scaled fp8 K=128 MFMA, BK=128 (4 sub-tiles of the R8-verified
// swizzled BK=32 layout). 19 K-iters/block vs 76 -> 4x fewer barrier drains.
// Lane's 32B A-operand = row m_in of sub-tile `quad`, halves at fxor / fxor^16.
// Bank check: m_in 0..7 span all 32 banks, 8 dwords/bank -> conflict-free minimum.
__global__ __launch_bounds__(256, 3)
void gemm_pv(const u8* __restrict__ A, const u8* __restrict__ B,
             u16* __restrict__ memC, int kChunk, size_t cPartStride)
{
  __shared__ __align__(16) u16 sbuf[16384];   // 32 KB: A 16K (4x4K sub-tiles) + B 16K
  u8* As8 = (u8*)sbuf;
  u8* Bs8 = (u8*)sbuf + 16384;

  const int tid  = threadIdx.x;
  const int wave = tid >> 6;
  const int lane = tid & 63;

  int b = blockIdx.x;
  int bz = b / 169;
  int rr = b - bz * 169;
  int gid = rr / 52;
  int rem = rr - gid * 52;
  int width = (gid < 3) ? 4 : 1;
  int bm = rem / width;
  int bn = gid * 4 + (rem - bm * width);

  const int kbeg = bz * kChunk;
  const int kend = kbeg + kChunk;

  const u8* Abase = A + (size_t)bm * 128 * BANK_P;
  const u8* Bbase = B + (size_t)bn * 128 * BANK_P;

  const int srow  = lane >> 1;
  const int shalf = (((lane & 1) ^ ((lane >> 3) & 1)) << 4);

  f32x4 acc[4][4];
#pragma unroll
  for (int i = 0; i < 4; i++)
#pragma unroll
    for (int j = 0; j < 4; j++) acc[i][j] = (f32x4){0.f, 0.f, 0.f, 0.f};

  const int m_in = lane & 15;
  const int quad = lane >> 4;
  const int wm = (wave >> 1) * 64;
  const int wn = (wave & 1) * 64;
  const int fxor = ((m_in >> 2) & 1) << 4;

  const size_t arow_off = (size_t)(wave * 32 + srow) * BANK_P;

  for (int kt = kbeg; kt < kend; kt += 128) {
#pragma unroll
    for (int s = 0; s < 4; s++)
      load_lds16(Abase + arow_off + kt + s * 32 + shalf, As8 + s * 4096 + wave * 1024);
#pragma unroll
    for (int s = 0; s < 4; s++)
      load_lds16(Bbase + arow_off + kt + s * 32 + shalf, Bs8 + s * 4096 + wave * 1024);
    __syncthreads();

    i32x8 a8[4];
#pragma unroll
    for (int i = 0; i < 4; i++) {
      const u8* p = As8 + quad * 4096 + (wm + i * 16 + m_in) * 32;
      u32x4 lo = *(const u32x4*)(p + fxor);
      u32x4 hi = *(const u32x4*)(p + (fxor ^ 16));
      a8[i] = (i32x8){(int)lo[0], (int)lo[1], (int)lo[2], (int)lo[3],
                      (int)hi[0], (int)hi[1], (int)hi[2], (int)hi[3]};
    }
#pragma unroll
    for (int j = 0; j < 4; j++) {
      const u8* p = Bs8 + quad * 4096 + (wn + j * 16 + m_in) * 32;
      u32x4 lo = *(const u32x4*)(p + fxor);
      u32x4 hi = *(const u32x4*)(p + (fxor ^ 16));
      i32x8 b8 = (i32x8){(int)lo[0], (int)lo[1], (int)lo[2], (int)lo[3],
                         (int)hi[0], (int)hi[1], (int)hi[2], (int)hi[3]};
#pragma unroll
      for (int i = 0; i < 4; i++)
        acc[i][j] = __builtin_amdgcn_mfma_scale_f32_16x16x128_f8f6f4(
            a8[i], b8, acc[i][j], 0, 0,              // cbsz=fp8, blgp=fp8
            0, 0x7f7f7f7f, 0, 0x7f7f7f7f);           // unit scales (E8M0 127 = x1)
    }
    __syncthreads();
  }

  // C-stage in two 16-KB halves (rows 0-63 by waves 0,1; rows 64-127 by waves 2,3)
  u16* Cg = memC + (size_t)bz * cPartStride;
#pragma unroll
  for (int h = 0; h < 2; h++) {
    __syncthreads();
    if ((wave >> 1) == h) {
#pragma unroll
      for (int i = 0; i < 4; i++)
#pragma unroll
        for (int j = 0; j < 4; j++)
#pragma unroll
          for (int t = 0; t < 4; t++) {
            int row_l = i * 16 + quad * 4 + t;      // row within half
            int col_l = wn + j * 16 + m_in;
            sbuf[(row_l << 7) + col_l] = f2bf(acc[i][j][t]);
          }
    }
    __syncthreads();
    for (int chunk = tid; chunk < 1024; chunk += 256) {
      int row = chunk >> 4;                         // 0..63
      int cu  = (chunk & 15) << 3;
      u32x4 v = *(const u32x4*)&sbuf[(row << 7) + cu];
      __builtin_nontemporal_store(
          v, (u32x4*)&Cg[(size_t)(bm * 128 + h * 64 + row) * LDCOL + bn * 128 + cu]);
    }
  }
}

// ---- epilogue: vec4 over n; lsum from memC row ONES_ROW ----
__global__ void epilogue(const u16* __restrict__ memC, const float* __restrict__ q_out,
                         float* __restrict__ out, int nParts) {
  const int NV = N_TOK / 4;                     // 405
  int idx = blockIdx.x * 256 + threadIdx.x;
  if (idx >= OBJ_N * 1024 * NV) return;
  int n4 = (idx % NV) * 4;
  int t = idx / NV;
  int c = t & 1023;
  int o = t >> 10;
  const size_t ps = (size_t)M_PAD * LDCOL;

  const u16* lbase = memC + (size_t)ONES_ROW * LDCOL + n4;
  float4 l = make_float4(0.f, 0.f, 0.f, 0.f);
  for (int z = 0; z < nParts; z++) {
    ushort4 v = *(const ushort4*)(lbase + z * ps);
    l.x += bf2f(v.x); l.y += bf2f(v.y); l.z += bf2f(v.z); l.w += bf2f(v.w);
  }

  size_t rowoff = (c < 512) ? (size_t)(o * 512 + c) * LDCOL
                            : (size_t)(1536 + o) * LDCOL;
  const u16* base = memC + rowoff + n4;
  float4 s = make_float4(0.f, 0.f, 0.f, 0.f);
  for (int z = 0; z < nParts; z++) {
    ushort4 v = *(const ushort4*)(base + z * ps);
    s.x += bf2f(v.x); s.y += bf2f(v.y); s.z += bf2f(v.z); s.w += bf2f(v.w);
  }
  float4 rv;
  float ix = 1.f / l.x, iy = 1.f / l.y, iz = 1.f / l.z, iw = 1.f / l.w;
  if (c < 512) {
    rv.x = s.x * ix; rv.y = s.y * iy; rv.z = s.z * iz; rv.w = s.w * iw;
  } else {
    float4 q = *(const float4*)(q_out + (size_t)(o * 512 + (c - 512)) * N_TOK + n4);
    rv.x = q.x * s.x * ix; rv.y = q.y * s.y * iy;
    rv.z = q.z * s.z * iz; rv.w = q.w * s.w * iw;
  }
  *(float4*)(out + (size_t)(o * 1024 + c) * N_TOK + n4) = rv;
}

extern "C" void kernel_launch(void* const* d_in, const int* in_sizes, int n_in,
                              void* d_out, int out_size, void* d_ws, size_t ws_size,
                              hipStream_t stream) {
  const float* keys   = (const float*)d_in[0];
  const float* q_in   = (const float*)d_in[1];
  const float* q_out  = (const float*)d_in[2];
  const float* values = (const float*)d_in[3];
  const float* masks  = (const float*)d_in[4];
  float* out = (float*)d_out;

  char* ws = (char*)d_ws;
  size_t off = 0;
  auto alloc = [&](size_t bytes) -> void* {
    void* p = ws + off; off += (bytes + 255) & ~(size_t)255; return p;
  };
  u16* qT  = (u16*)alloc((size_t)N_PAD * D_KEY * 2);
  u16* kT  = (u16*)alloc((size_t)BANK_P * D_KEY * 2);
  u8*  vm8 = (u8*)alloc((size_t)M_PAD * BANK_P);
  u8*  E8  = (u8*)alloc((size_t)N_PAD * BANK_P);

  int nParts = 4;
  while (nParts > 1 && off + (size_t)nParts * M_PAD * LDCOL * 2 > ws_size) nParts >>= 1;
  u16* memC = (u16*)alloc((size_t)nParts * M_PAD * LDCOL * 2);

  const int vmBlocks = (M_PAD * (BANK_P / 4) + 255) / 256;   // 15808
  prep<<<1136 + vmBlocks, 256, 0, stream>>>(q_in, keys, values, masks, qT, kT, vm8);

  gemm_qk<<<988, 256, 0, stream>>>(qT, kT, E8);

  int kChunk = BANK_P / nParts;                // 2432 = 19 * 128
  gemm_pv<<<dim3(169 * nParts), 256, 0, stream>>>(vm8, E8, memC, kChunk, (size_t)M_PAD * LDCOL);

  epilogue<<<(OBJ_N * 1024 * (N_TOK / 4) + 255) / 256, 256, 0, stream>>>(
      memC, q_out, out, nParts);
}